// Round 8
// baseline (579.013 us; speedup 1.0000x reference)
//
#include <hip/hip_runtime.h>

#define N_NODES  100000
#define N_EDGES  1250000
#define F_IN     128
#define F_OUT    64
#define N_GRAPHS 256
#define SCAN_BLK 1024
#define N_SBLK   98
#define NB_LIN   1563          // ceil(100000/64)
#define NB_DEG   2442          // 625152 threads; 2 independent atomics each
#define E_HALF   625000
#define FILL_B   1221          // 4 edges/thread scatter section
#define FILL_T   (FILL_B * 256)
#define YB       1024          // y = dis*z section blocks
#define GB       64            // gather: nodes per block

typedef __attribute__((ext_vector_type(8))) short short8;   // 8 bf16 (4 VGPRs)
typedef __attribute__((ext_vector_type(8))) unsigned short ushort8;
typedef __attribute__((ext_vector_type(4))) float f32x4;

static __device__ __forceinline__ unsigned short f2bf(float f) {
    unsigned u = __builtin_bit_cast(unsigned, f);
    u += 0x7fff + ((u >> 16) & 1);            // RNE
    return (unsigned short)(u >> 16);
}
static __device__ __forceinline__ float bf2f(unsigned short h) {
    unsigned u = ((unsigned)h) << 16;
    return __builtin_bit_cast(float, u);
}

// ---------------- fused: MFMA linear (z = x@W^T, bf16) + degree/rank count ----------------
__global__ __launch_bounds__(256) void lin_deg_k(const float* __restrict__ x,
                                                 const float* __restrict__ W,
                                                 unsigned short* __restrict__ z,
                                                 const int* __restrict__ col,
                                                 int* __restrict__ deg,
                                                 int* __restrict__ rank) {
    if (blockIdx.x >= NB_LIN) {
        int t = (blockIdx.x - NB_LIN) * 256 + threadIdx.x;
        if (t < E_HALF) {
            int e0 = t, e1 = t + E_HALF;
            int c0 = col[e0], c1 = col[e1];          // independent
            int p0 = atomicAdd(&deg[c0], 1);         // both atomics in flight
            int p1 = atomicAdd(&deg[c1], 1);
            rank[e0] = p0;                           // coalesced stores
            rank[e1] = p1;
        }
        return;
    }

    // bf16 tiles, XOR-swizzled so MFMA fragment b128 reads are conflict-free
    __shared__ unsigned xs[64 * 64];   // 16 KB: 64 nodes x 128 k
    __shared__ unsigned ws[64 * 64];   // 16 KB: 64 feats x 128 k
    int tid  = threadIdx.x;
    int base = blockIdx.x * 64;
    int nmax = N_NODES - base; if (nmax > 64) nmax = 64;   // last block: 32

    #pragma unroll
    for (int rr = 0; rr < 8; ++rr) {
        int idx = rr * 256 + tid;          // 0..2047
        int n = idx >> 5, q = idx & 31;    // row, float4-index (k = 4q)
        int d   = (n << 6) + (q << 1);     // dword offset: n*64 + 2q
        int sdw = (n & 7) << 2;            // swizzle (bytes<<4 -> dwords<<2)
        const float4 wv = *(const float4*)(W + (size_t)n * F_IN + q * 4);
        ws[(d ^ sdw)]     = (unsigned)f2bf(wv.x) | ((unsigned)f2bf(wv.y) << 16);
        ws[(d ^ sdw) + 1] = (unsigned)f2bf(wv.z) | ((unsigned)f2bf(wv.w) << 16);
        float4 xv = make_float4(0.f, 0.f, 0.f, 0.f);
        if (n < nmax) xv = *(const float4*)(x + (size_t)(base + n) * F_IN + q * 4);
        xs[(d ^ sdw)]     = (unsigned)f2bf(xv.x) | ((unsigned)f2bf(xv.y) << 16);
        xs[(d ^ sdw) + 1] = (unsigned)f2bf(xv.z) | ((unsigned)f2bf(xv.w) << 16);
    }
    __syncthreads();

    int lane = tid & 63;
    int wv_  = tid >> 6;          // wave 0..3
    int m0   = wv_ << 4;          // node base within tile
    int lr   = lane & 15;
    int lg   = lane >> 4;         // 0..3

    f32x4 acc0 = (f32x4)(0.f), acc1 = (f32x4)(0.f);
    f32x4 acc2 = (f32x4)(0.f), acc3 = (f32x4)(0.f);

    #pragma unroll
    for (int t = 0; t < 4; ++t) {          // k-tiles of 32
        int nn = m0 + lr;
        int da = ((nn << 6) + (t << 4) + (lg << 2)) ^ ((nn & 7) << 2);
        short8 a = *(const short8*)(xs + da);
        #pragma unroll
        for (int ff = 0; ff < 4; ++ff) {   // feature tiles of 16
            int f  = (ff << 4) + lr;
            int db = ((f << 6) + (t << 4) + (lg << 2)) ^ ((f & 7) << 2);
            short8 b = *(const short8*)(ws + db);
            f32x4 c = (ff == 0) ? acc0 : (ff == 1) ? acc1 : (ff == 2) ? acc2 : acc3;
            c = __builtin_amdgcn_mfma_f32_16x16x32_bf16(a, b, c, 0, 0, 0);
            if (ff == 0) acc0 = c; else if (ff == 1) acc1 = c;
            else if (ff == 2) acc2 = c; else acc3 = c;
        }
    }

    // D layout: feat = ff*16 + (lane&15), node = m0 + (lane>>4)*4 + r
    #pragma unroll
    for (int r = 0; r < 4; ++r) {
        int node = m0 + (lg << 2) + r;
        if (node < nmax) {
            size_t o = (size_t)(base + node) * F_OUT + lr;
            z[o +  0] = f2bf(acc0[r]);
            z[o + 16] = f2bf(acc1[r]);
            z[o + 32] = f2bf(acc2[r]);
            z[o + 48] = f2bf(acc3[r]);
        }
    }
}

// ---------------- exclusive scan of deg -> offs ----------------
__global__ __launch_bounds__(SCAN_BLK) void scan1_k(const int* __restrict__ deg,
                                                    int* __restrict__ offs,
                                                    int* __restrict__ bsum) {
    __shared__ int lds[SCAN_BLK];
    int tid = threadIdx.x;
    int i = blockIdx.x * SCAN_BLK + tid;
    int v = (i < N_NODES) ? deg[i] : 0;
    lds[tid] = v;
    __syncthreads();
    for (int off = 1; off < SCAN_BLK; off <<= 1) {
        int t = (tid >= off) ? lds[tid - off] : 0;
        __syncthreads();
        lds[tid] += t;
        __syncthreads();
    }
    if (i < N_NODES) offs[i] = lds[tid] - v;
    if (tid == SCAN_BLK - 1) bsum[blockIdx.x] = lds[tid];
}

__global__ __launch_bounds__(128) void scan2_k(int* __restrict__ bsum) {
    __shared__ int lds[128];
    int tid = threadIdx.x;
    int v = (tid < N_SBLK) ? bsum[tid] : 0;
    lds[tid] = v;
    __syncthreads();
    for (int off = 1; off < 128; off <<= 1) {
        int t = (tid >= off) ? lds[tid - off] : 0;
        __syncthreads();
        lds[tid] += t;
        __syncthreads();
    }
    if (tid < N_SBLK) bsum[tid] = lds[tid] - v;
}

// scan3 + dis = rsqrt(deg+1) fused
__global__ __launch_bounds__(SCAN_BLK) void scan3_k(int* __restrict__ offs,
                                                    const int* __restrict__ bsum,
                                                    const int* __restrict__ deg,
                                                    float* __restrict__ dis) {
    int i = blockIdx.x * SCAN_BLK + threadIdx.x;
    if (i < N_NODES) {
        offs[i] = offs[i] + bsum[blockIdx.x];
        dis[i] = rsqrtf((float)deg[i] + 1.0f);
    }
}

// ---------------- fused: fill CSR bucket (atomic-free) + y = dis*z (bf16) ----------------
__global__ __launch_bounds__(256) void fill_y_k(const int* __restrict__ row,
                                                const int* __restrict__ col,
                                                const int* __restrict__ offs,
                                                const int* __restrict__ rank,
                                                int* __restrict__ bucket,
                                                const unsigned short* __restrict__ z,
                                                const float* __restrict__ dis,
                                                unsigned short* __restrict__ y) {
    if (blockIdx.x < FILL_B) {
        int t = blockIdx.x * 256 + threadIdx.x;
        #pragma unroll
        for (int u = 0; u < 4; ++u) {
            int e = t + u * FILL_T;
            if (e < N_EDGES) {
                int c = col[e];                       // coalesced
                bucket[offs[c] + rank[e]] = row[e];   // L2 gather + scattered store
            }
        }
        return;
    }
    // y section: 800000 ushort8 chunks (8 bf16 each)
    int t = (blockIdx.x - FILL_B) * 256 + threadIdx.x;
    for (int c = t; c < (N_NODES * F_OUT) / 8; c += YB * 256) {
        ushort8 v = ((const ushort8*)z)[c];
        float d = dis[c >> 3];
        ushort8 o;
        #pragma unroll
        for (int k = 0; k < 8; ++k) o[k] = f2bf(d * bf2f(v[k]));
        ((ushort8*)y)[c] = o;
    }
}

// ---------------- gather_v2: edge-parallel, LDS accumulate + relu/bias + pool ----------------
// Block owns GB=64 nodes. accL[node][feat] in LDS; waves walk contiguous
// sub-segments of the block's CSR range with 8-deep independent y-gathers
// feeding fire-and-forget LDS float atomics. Slot->node via monotone pointer.
__global__ __launch_bounds__(256) void gather_pool_k(const unsigned short* __restrict__ y,
                                                     const int* __restrict__ offs,
                                                     const int* __restrict__ bucket,
                                                     const float* __restrict__ dis,
                                                     const int* __restrict__ batch,
                                                     const float* __restrict__ bias,
                                                     float* __restrict__ psum,
                                                     int* __restrict__ pcnt) {
    __shared__ float accL[GB * F_OUT];     // 16 KB
    __shared__ int   offsL[GB + 1];
    int tid  = threadIdx.x;
    int lane = tid & 63;
    int wid  = tid >> 6;
    int base = blockIdx.x * GB;
    int nmax = N_NODES - base; if (nmax > GB) nmax = GB;   // last block: 32

    if (tid < nmax) offsL[tid] = offs[base + tid];
    if (tid == nmax) offsL[nmax] = (base + nmax < N_NODES) ? offs[base + nmax] : N_EDGES;
    // init accumulators with self-loop term y[i]
    for (int n = wid; n < nmax; n += 4)
        accL[n * F_OUT + lane] = bf2f(y[(size_t)(base + n) * F_OUT + lane]);
    __syncthreads();

    int s0 = offsL[0], s1 = offsL[nmax];
    int L  = s1 - s0;
    int ws = s0 + (int)(((long long)L * wid) >> 2);
    int we = s0 + (int)(((long long)L * (wid + 1)) >> 2);

    int cur = 0;
    while (cur < nmax - 1 && offsL[cur + 1] <= ws) ++cur;

    int j = ws;
    for (; j + 7 < we; j += 8) {
        int r0 = bucket[j],     r1 = bucket[j + 1], r2 = bucket[j + 2], r3 = bucket[j + 3];
        int r4 = bucket[j + 4], r5 = bucket[j + 5], r6 = bucket[j + 6], r7 = bucket[j + 7];
        float v0 = bf2f(y[(size_t)r0 * F_OUT + lane]);
        float v1 = bf2f(y[(size_t)r1 * F_OUT + lane]);
        float v2 = bf2f(y[(size_t)r2 * F_OUT + lane]);
        float v3 = bf2f(y[(size_t)r3 * F_OUT + lane]);
        float v4 = bf2f(y[(size_t)r4 * F_OUT + lane]);
        float v5 = bf2f(y[(size_t)r5 * F_OUT + lane]);
        float v6 = bf2f(y[(size_t)r6 * F_OUT + lane]);
        float v7 = bf2f(y[(size_t)r7 * F_OUT + lane]);
        int n0, n1, n2, n3, n4, n5, n6, n7;
        while (j     >= offsL[cur + 1]) ++cur;  n0 = cur;
        while (j + 1 >= offsL[cur + 1]) ++cur;  n1 = cur;
        while (j + 2 >= offsL[cur + 1]) ++cur;  n2 = cur;
        while (j + 3 >= offsL[cur + 1]) ++cur;  n3 = cur;
        while (j + 4 >= offsL[cur + 1]) ++cur;  n4 = cur;
        while (j + 5 >= offsL[cur + 1]) ++cur;  n5 = cur;
        while (j + 6 >= offsL[cur + 1]) ++cur;  n6 = cur;
        while (j + 7 >= offsL[cur + 1]) ++cur;  n7 = cur;
        atomicAdd(&accL[n0 * F_OUT + lane], v0);
        atomicAdd(&accL[n1 * F_OUT + lane], v1);
        atomicAdd(&accL[n2 * F_OUT + lane], v2);
        atomicAdd(&accL[n3 * F_OUT + lane], v3);
        atomicAdd(&accL[n4 * F_OUT + lane], v4);
        atomicAdd(&accL[n5 * F_OUT + lane], v5);
        atomicAdd(&accL[n6 * F_OUT + lane], v6);
        atomicAdd(&accL[n7 * F_OUT + lane], v7);
    }
    for (; j < we; ++j) {
        int r = bucket[j];
        float v = bf2f(y[(size_t)r * F_OUT + lane]);
        while (j >= offsL[cur + 1]) ++cur;
        atomicAdd(&accL[cur * F_OUT + lane], v);
    }
    __syncthreads();

    // finish: relu(dis*acc + bias), run-length mean-pool (batch sorted)
    int nlo = wid * 16;
    int nhi = nlo + 16; if (nhi > nmax) nhi = nmax;
    float bf = bias[lane];
    float racc = 0.f;
    int curg = -1, runlen = 0;
    for (int n = nlo; n < nhi; ++n) {
        int i = base + n;
        float v = fmaxf(fmaf(dis[i], accL[n * F_OUT + lane], bf), 0.f);
        int g = batch[i];
        if (g != curg) {
            if (curg >= 0) {
                atomicAdd(&psum[curg * F_OUT + lane], racc);
                if (lane == 0) atomicAdd(&pcnt[curg], runlen);
            }
            curg = g; racc = 0.f; runlen = 0;
        }
        racc += v; runlen++;
    }
    if (curg >= 0) {
        atomicAdd(&psum[curg * F_OUT + lane], racc);
        if (lane == 0) atomicAdd(&pcnt[curg], runlen);
    }
}

// ---------------- out = psum / max(count,1) ----------------
__global__ __launch_bounds__(256) void final_k(const float* __restrict__ psum,
                                               const int* __restrict__ pcnt,
                                               float* __restrict__ out) {
    int t = blockIdx.x * blockDim.x + threadIdx.x;
    if (t < N_GRAPHS * F_OUT) {
        int g = t >> 6;
        float c = (float)(pcnt[g] > 1 ? pcnt[g] : 1);
        out[t] = psum[t] / c;
    }
}

extern "C" void kernel_launch(void* const* d_in, const int* in_sizes, int n_in,
                              void* d_out, int out_size, void* d_ws, size_t ws_size,
                              hipStream_t stream) {
    const float* node_feat = (const float*)d_in[0];
    const int*   edges     = (const int*)d_in[1];   // [2, E] flat: row then col
    const int*   batch     = (const int*)d_in[2];
    const float* W         = (const float*)d_in[3];
    const float* b         = (const float*)d_in[4];

    // workspace carve-up (~38 MB)
    unsigned short* z = (unsigned short*)d_ws;              // N*64 bf16
    int*   deg    = (int*)(z + (size_t)N_NODES * F_OUT);    // N
    float* psum   = (float*)(deg + N_NODES);                // G*64
    int*   pcnt   = (int*)(psum + N_GRAPHS * F_OUT);        // G
    float* dis    = (float*)(pcnt + N_GRAPHS);              // N
    int*   offs   = (int*)(dis + N_NODES);                  // N
    int*   bsum   = offs + N_NODES;                         // 128
    int*   bucket = bsum + 128;                             // E
    int*   rank   = bucket + N_EDGES;                       // E
    unsigned short* y = (unsigned short*)(rank + N_EDGES);  // N*64 bf16

    // zero deg + psum + pcnt (contiguous)
    size_t zbytes = ((size_t)N_NODES + N_GRAPHS * F_OUT + N_GRAPHS) * 4;
    hipMemsetAsync(deg, 0, zbytes, stream);

    const int* row = edges;
    const int* col = edges + N_EDGES;

    lin_deg_k<<<NB_LIN + NB_DEG, 256, 0, stream>>>(node_feat, W, z, col, deg, rank);
    scan1_k<<<N_SBLK, SCAN_BLK, 0, stream>>>(deg, offs, bsum);
    scan2_k<<<1, 128, 0, stream>>>(bsum);
    scan3_k<<<N_SBLK, SCAN_BLK, 0, stream>>>(offs, bsum, deg, dis);
    fill_y_k<<<FILL_B + YB, 256, 0, stream>>>(row, col, offs, rank, bucket, z, dis, y);
    gather_pool_k<<<(N_NODES + GB - 1) / GB, 256, 0, stream>>>(y, offs, bucket,
                                                               dis, batch, b, psum, pcnt);
    final_k<<<(N_GRAPHS * F_OUT + 255) / 256, 256, 0, stream>>>(psum, pcnt, (float*)d_out);
}

// Round 9
// 195.875 us; speedup vs baseline: 2.9560x; 2.9560x over previous
//
#include <hip/hip_runtime.h>

#define N_NODES  100000
#define N_EDGES  1250000
#define F_IN     128
#define F_OUT    64
#define N_GRAPHS 256
#define SCAN_BLK 1024
#define N_SBLK   98
#define NB_LIN   1563          // ceil(100000/64)
#define NB_DEG   2442          // 625152 threads; 2 independent atomics each
#define E_HALF   625000
#define FILL_B   1221          // 4 edges/thread scatter section
#define FILL_T   (FILL_B * 256)
#define YB       1024          // y = dis*z section blocks

typedef __attribute__((ext_vector_type(8))) short short8;   // 8 bf16 (4 VGPRs)
typedef __attribute__((ext_vector_type(8))) unsigned short ushort8;
typedef __attribute__((ext_vector_type(4))) float f32x4;

static __device__ __forceinline__ unsigned short f2bf(float f) {
    unsigned u = __builtin_bit_cast(unsigned, f);
    u += 0x7fff + ((u >> 16) & 1);            // RNE
    return (unsigned short)(u >> 16);
}
static __device__ __forceinline__ float bf2f(unsigned short h) {
    unsigned u = ((unsigned)h) << 16;
    return __builtin_bit_cast(float, u);
}
static __device__ __forceinline__ float bflo(unsigned v) {   // low bf16 of packed u32
    return __builtin_bit_cast(float, v << 16);
}
static __device__ __forceinline__ float bfhi(unsigned v) {   // high bf16 of packed u32
    return __builtin_bit_cast(float, v & 0xffff0000u);
}

// ---------------- fused: MFMA linear (z = x@W^T, bf16) + degree/rank count ----------------
__global__ __launch_bounds__(256) void lin_deg_k(const float* __restrict__ x,
                                                 const float* __restrict__ W,
                                                 unsigned short* __restrict__ z,
                                                 const int* __restrict__ col,
                                                 int* __restrict__ deg,
                                                 int* __restrict__ rank) {
    if (blockIdx.x >= NB_LIN) {
        int t = (blockIdx.x - NB_LIN) * 256 + threadIdx.x;
        if (t < E_HALF) {
            int e0 = t, e1 = t + E_HALF;
            int c0 = col[e0], c1 = col[e1];          // independent
            int p0 = atomicAdd(&deg[c0], 1);         // both atomics in flight
            int p1 = atomicAdd(&deg[c1], 1);
            rank[e0] = p0;                           // coalesced stores
            rank[e1] = p1;
        }
        return;
    }

    // bf16 tiles, XOR-swizzled so MFMA fragment b128 reads are conflict-free
    __shared__ unsigned xs[64 * 64];   // 16 KB: 64 nodes x 128 k
    __shared__ unsigned ws[64 * 64];   // 16 KB: 64 feats x 128 k
    int tid  = threadIdx.x;
    int base = blockIdx.x * 64;
    int nmax = N_NODES - base; if (nmax > 64) nmax = 64;   // last block: 32

    #pragma unroll
    for (int rr = 0; rr < 8; ++rr) {
        int idx = rr * 256 + tid;          // 0..2047
        int n = idx >> 5, q = idx & 31;    // row, float4-index (k = 4q)
        int d   = (n << 6) + (q << 1);     // dword offset: n*64 + 2q
        int sdw = (n & 7) << 2;            // swizzle (bytes<<4 -> dwords<<2)
        const float4 wv = *(const float4*)(W + (size_t)n * F_IN + q * 4);
        ws[(d ^ sdw)]     = (unsigned)f2bf(wv.x) | ((unsigned)f2bf(wv.y) << 16);
        ws[(d ^ sdw) + 1] = (unsigned)f2bf(wv.z) | ((unsigned)f2bf(wv.w) << 16);
        float4 xv = make_float4(0.f, 0.f, 0.f, 0.f);
        if (n < nmax) xv = *(const float4*)(x + (size_t)(base + n) * F_IN + q * 4);
        xs[(d ^ sdw)]     = (unsigned)f2bf(xv.x) | ((unsigned)f2bf(xv.y) << 16);
        xs[(d ^ sdw) + 1] = (unsigned)f2bf(xv.z) | ((unsigned)f2bf(xv.w) << 16);
    }
    __syncthreads();

    int lane = tid & 63;
    int wv_  = tid >> 6;          // wave 0..3
    int m0   = wv_ << 4;          // node base within tile
    int lr   = lane & 15;
    int lg   = lane >> 4;         // 0..3

    f32x4 acc0 = (f32x4)(0.f), acc1 = (f32x4)(0.f);
    f32x4 acc2 = (f32x4)(0.f), acc3 = (f32x4)(0.f);

    #pragma unroll
    for (int t = 0; t < 4; ++t) {          // k-tiles of 32
        int nn = m0 + lr;
        int da = ((nn << 6) + (t << 4) + (lg << 2)) ^ ((nn & 7) << 2);
        short8 a = *(const short8*)(xs + da);
        #pragma unroll
        for (int ff = 0; ff < 4; ++ff) {   // feature tiles of 16
            int f  = (ff << 4) + lr;
            int db = ((f << 6) + (t << 4) + (lg << 2)) ^ ((f & 7) << 2);
            short8 b = *(const short8*)(ws + db);
            f32x4 c = (ff == 0) ? acc0 : (ff == 1) ? acc1 : (ff == 2) ? acc2 : acc3;
            c = __builtin_amdgcn_mfma_f32_16x16x32_bf16(a, b, c, 0, 0, 0);
            if (ff == 0) acc0 = c; else if (ff == 1) acc1 = c;
            else if (ff == 2) acc2 = c; else acc3 = c;
        }
    }

    // D layout: feat = ff*16 + (lane&15), node = m0 + (lane>>4)*4 + r
    #pragma unroll
    for (int r = 0; r < 4; ++r) {
        int node = m0 + (lg << 2) + r;
        if (node < nmax) {
            size_t o = (size_t)(base + node) * F_OUT + lr;
            z[o +  0] = f2bf(acc0[r]);
            z[o + 16] = f2bf(acc1[r]);
            z[o + 32] = f2bf(acc2[r]);
            z[o + 48] = f2bf(acc3[r]);
        }
    }
}

// ---------------- exclusive scan of deg -> offs ----------------
__global__ __launch_bounds__(SCAN_BLK) void scan1_k(const int* __restrict__ deg,
                                                    int* __restrict__ offs,
                                                    int* __restrict__ bsum) {
    __shared__ int lds[SCAN_BLK];
    int tid = threadIdx.x;
    int i = blockIdx.x * SCAN_BLK + tid;
    int v = (i < N_NODES) ? deg[i] : 0;
    lds[tid] = v;
    __syncthreads();
    for (int off = 1; off < SCAN_BLK; off <<= 1) {
        int t = (tid >= off) ? lds[tid - off] : 0;
        __syncthreads();
        lds[tid] += t;
        __syncthreads();
    }
    if (i < N_NODES) offs[i] = lds[tid] - v;
    if (tid == SCAN_BLK - 1) bsum[blockIdx.x] = lds[tid];
}

__global__ __launch_bounds__(128) void scan2_k(int* __restrict__ bsum) {
    __shared__ int lds[128];
    int tid = threadIdx.x;
    int v = (tid < N_SBLK) ? bsum[tid] : 0;
    lds[tid] = v;
    __syncthreads();
    for (int off = 1; off < 128; off <<= 1) {
        int t = (tid >= off) ? lds[tid - off] : 0;
        __syncthreads();
        lds[tid] += t;
        __syncthreads();
    }
    if (tid < N_SBLK) bsum[tid] = lds[tid] - v;
}

// scan3 + dis = rsqrt(deg+1) fused
__global__ __launch_bounds__(SCAN_BLK) void scan3_k(int* __restrict__ offs,
                                                    const int* __restrict__ bsum,
                                                    const int* __restrict__ deg,
                                                    float* __restrict__ dis) {
    int i = blockIdx.x * SCAN_BLK + threadIdx.x;
    if (i < N_NODES) {
        offs[i] = offs[i] + bsum[blockIdx.x];
        dis[i] = rsqrtf((float)deg[i] + 1.0f);
    }
}

// ---------------- fused: fill CSR bucket (atomic-free) + y = dis*z (bf16) ----------------
__global__ __launch_bounds__(256) void fill_y_k(const int* __restrict__ row,
                                                const int* __restrict__ col,
                                                const int* __restrict__ offs,
                                                const int* __restrict__ rank,
                                                int* __restrict__ bucket,
                                                const unsigned short* __restrict__ z,
                                                const float* __restrict__ dis,
                                                unsigned short* __restrict__ y) {
    if (blockIdx.x < FILL_B) {
        int t = blockIdx.x * 256 + threadIdx.x;
        #pragma unroll
        for (int u = 0; u < 4; ++u) {
            int e = t + u * FILL_T;
            if (e < N_EDGES) {
                int c = col[e];                       // coalesced
                bucket[offs[c] + rank[e]] = row[e];   // L2 gather + scattered store
            }
        }
        return;
    }
    // y section: 800000 ushort8 chunks (8 bf16 each)
    int t = (blockIdx.x - FILL_B) * 256 + threadIdx.x;
    for (int c = t; c < (N_NODES * F_OUT) / 8; c += YB * 256) {
        ushort8 v = ((const ushort8*)z)[c];
        float d = dis[c >> 3];
        ushort8 o;
        #pragma unroll
        for (int k = 0; k < 8; ++k) o[k] = f2bf(d * bf2f(v[k]));
        ((ushort8*)y)[c] = o;
    }
}

// ---------------- gather_v3: register acc, half-wave edge pairing ----------------
// Wave handles 8 consecutive nodes. lane = (eo = lane>>5 edge slot, fp = lane&31
// feature pair). Per instruction: 2 edges x 32 feature-pairs (u32 = 2 bf16).
// 8-pair unroll -> 16 edges in flight. y is pre-scaled (dis folded): no dis loads.
__global__ __launch_bounds__(256) void gather_pool_k(const unsigned short* __restrict__ y,
                                                     const int* __restrict__ offs,
                                                     const int* __restrict__ deg,
                                                     const int* __restrict__ bucket,
                                                     const float* __restrict__ dis,
                                                     const int* __restrict__ batch,
                                                     const float* __restrict__ bias,
                                                     float* __restrict__ psum,
                                                     int* __restrict__ pcnt) {
    int lane = threadIdx.x & 63;
    int wid  = threadIdx.x >> 6;
    int i0   = (blockIdx.x * 4 + wid) * 8;   // 100000 = 3125 * 32
    int eo   = lane >> 5;                    // edge slot 0/1
    int fp   = lane & 31;                    // feature pair: feats 2fp, 2fp+1
    float bx = bias[2 * fp], by = bias[2 * fp + 1];

    float rx = 0.f, ry = 0.f;                // pool run accumulator
    int cur = -1, runlen = 0;
    for (int n = 0; n < 8; ++n) {
        int i = i0 + n;
        int s = __builtin_amdgcn_readfirstlane(offs[i]);
        int e = s + __builtin_amdgcn_readfirstlane(deg[i]);

        // self-loop term, counted once (slot 0 only; slot 1 contributes 0)
        float ax = 0.f, ay = 0.f;
        if (eo == 0) {
            unsigned v = *(const unsigned*)(y + (size_t)i * F_OUT + 2 * fp);
            ax = bflo(v); ay = bfhi(v);
        }

        for (int j = s; j < e; j += 16) {
            #pragma unroll
            for (int u = 0; u < 8; ++u) {
                int idx = j + 2 * u + eo;
                if (idx < e) {
                    int r = bucket[idx];
                    unsigned v = *(const unsigned*)(y + (size_t)r * F_OUT + 2 * fp);
                    ax += bflo(v); ay += bfhi(v);
                }
            }
        }
        // combine the two edge slots (both halves end with the full sum)
        ax += __shfl_xor(ax, 32);
        ay += __shfl_xor(ay, 32);

        float di = dis[i];
        float vx = fmaxf(fmaf(di, ax, bx), 0.f);
        float vy = fmaxf(fmaf(di, ay, by), 0.f);
        int g = batch[i];
        if (g != cur) {
            if (cur >= 0 && eo == 0) {
                atomicAdd(&psum[cur * F_OUT + 2 * fp],     rx);
                atomicAdd(&psum[cur * F_OUT + 2 * fp + 1], ry);
                if (lane == 0) atomicAdd(&pcnt[cur], runlen);
            }
            cur = g; rx = 0.f; ry = 0.f; runlen = 0;
        }
        rx += vx; ry += vy; runlen++;
    }
    if (cur >= 0 && eo == 0) {
        atomicAdd(&psum[cur * F_OUT + 2 * fp],     rx);
        atomicAdd(&psum[cur * F_OUT + 2 * fp + 1], ry);
        if (lane == 0) atomicAdd(&pcnt[cur], runlen);
    }
}

// ---------------- out = psum / max(count,1) ----------------
__global__ __launch_bounds__(256) void final_k(const float* __restrict__ psum,
                                               const int* __restrict__ pcnt,
                                               float* __restrict__ out) {
    int t = blockIdx.x * blockDim.x + threadIdx.x;
    if (t < N_GRAPHS * F_OUT) {
        int g = t >> 6;
        float c = (float)(pcnt[g] > 1 ? pcnt[g] : 1);
        out[t] = psum[t] / c;
    }
}

extern "C" void kernel_launch(void* const* d_in, const int* in_sizes, int n_in,
                              void* d_out, int out_size, void* d_ws, size_t ws_size,
                              hipStream_t stream) {
    const float* node_feat = (const float*)d_in[0];
    const int*   edges     = (const int*)d_in[1];   // [2, E] flat: row then col
    const int*   batch     = (const int*)d_in[2];
    const float* W         = (const float*)d_in[3];
    const float* b         = (const float*)d_in[4];

    // workspace carve-up (~38 MB)
    unsigned short* z = (unsigned short*)d_ws;              // N*64 bf16
    int*   deg    = (int*)(z + (size_t)N_NODES * F_OUT);    // N
    float* psum   = (float*)(deg + N_NODES);                // G*64
    int*   pcnt   = (int*)(psum + N_GRAPHS * F_OUT);        // G
    float* dis    = (float*)(pcnt + N_GRAPHS);              // N
    int*   offs   = (int*)(dis + N_NODES);                  // N
    int*   bsum   = offs + N_NODES;                         // 128
    int*   bucket = bsum + 128;                             // E
    int*   rank   = bucket + N_EDGES;                       // E
    unsigned short* y = (unsigned short*)(rank + N_EDGES);  // N*64 bf16

    // zero deg + psum + pcnt (contiguous)
    size_t zbytes = ((size_t)N_NODES + N_GRAPHS * F_OUT + N_GRAPHS) * 4;
    hipMemsetAsync(deg, 0, zbytes, stream);

    const int* row = edges;
    const int* col = edges + N_EDGES;

    lin_deg_k<<<NB_LIN + NB_DEG, 256, 0, stream>>>(node_feat, W, z, col, deg, rank);
    scan1_k<<<N_SBLK, SCAN_BLK, 0, stream>>>(deg, offs, bsum);
    scan2_k<<<1, 128, 0, stream>>>(bsum);
    scan3_k<<<N_SBLK, SCAN_BLK, 0, stream>>>(offs, bsum, deg, dis);
    fill_y_k<<<FILL_B + YB, 256, 0, stream>>>(row, col, offs, rank, bucket, z, dis, y);
    gather_pool_k<<<N_NODES / 32, 256, 0, stream>>>(y, offs, deg, bucket,
                                                    dis, batch, b, psum, pcnt);
    final_k<<<(N_GRAPHS * F_OUT + 255) / 256, 256, 0, stream>>>(psum, pcnt, (float*)d_out);
}

// Round 10
// 161.043 us; speedup vs baseline: 3.5954x; 1.2163x over previous
//
#include <hip/hip_runtime.h>

#define N_NODES  100000
#define N_EDGES  1250000
#define F_IN     128
#define F_OUT    64
#define N_GRAPHS 256
#define SCAN_BLK 1024
#define N_SBLK   98
#define NB_LIN   1563          // total 64-node tiles
#define NB_LINB  391           // MFMA blocks; 4 tiles each, W staged once
#define NB_DEG   2442          // 625152 threads; 2 independent atomics each
#define E_HALF   625000
#define FILL_B   1221          // 4 edges/thread scatter section
#define FILL_T   (FILL_B * 256)
#define YB       1024          // y = dis*z section blocks

typedef __attribute__((ext_vector_type(8))) short short8;   // 8 bf16 (4 VGPRs)
typedef __attribute__((ext_vector_type(8))) unsigned short ushort8;
typedef __attribute__((ext_vector_type(4))) float f32x4;

static __device__ __forceinline__ unsigned short f2bf(float f) {
    unsigned u = __builtin_bit_cast(unsigned, f);
    u += 0x7fff + ((u >> 16) & 1);            // RNE
    return (unsigned short)(u >> 16);
}
static __device__ __forceinline__ float bf2f(unsigned short h) {
    unsigned u = ((unsigned)h) << 16;
    return __builtin_bit_cast(float, u);
}

// ---------------- fused: MFMA linear (z = x@W^T, bf16) + degree/rank count ----------------
// Blocks [0, NB_LINB): 4 node-tiles each, W staged once. Blocks [NB_LINB, ...):
// rank[e] = atomicAdd(&deg[col[e]], 1), 2 independent atomics/thread.
__global__ __launch_bounds__(256) void lin_deg_k(const float* __restrict__ x,
                                                 const float* __restrict__ W,
                                                 unsigned short* __restrict__ z,
                                                 const int* __restrict__ col,
                                                 int* __restrict__ deg,
                                                 int* __restrict__ rank) {
    if (blockIdx.x >= NB_LINB) {
        int t = (blockIdx.x - NB_LINB) * 256 + threadIdx.x;
        if (t < E_HALF) {
            int e0 = t, e1 = t + E_HALF;
            int c0 = col[e0], c1 = col[e1];          // independent
            int p0 = atomicAdd(&deg[c0], 1);         // both atomics in flight
            int p1 = atomicAdd(&deg[c1], 1);
            rank[e0] = p0;                           // coalesced stores
            rank[e1] = p1;
        }
        return;
    }

    __shared__ unsigned xs[64 * 64];   // 16 KB: 64 nodes x 128 k (bf16 pairs)
    __shared__ unsigned ws[64 * 64];   // 16 KB: 64 feats x 128 k
    int tid  = threadIdx.x;

    // stage W ONCE (re-used across 4 tiles)
    #pragma unroll
    for (int rr = 0; rr < 8; ++rr) {
        int idx = rr * 256 + tid;          // 0..2047
        int n = idx >> 5, q = idx & 31;
        int d   = (n << 6) + (q << 1);
        int sdw = (n & 7) << 2;
        const float4 wv = *(const float4*)(W + (size_t)n * F_IN + q * 4);
        ws[(d ^ sdw)]     = (unsigned)f2bf(wv.x) | ((unsigned)f2bf(wv.y) << 16);
        ws[(d ^ sdw) + 1] = (unsigned)f2bf(wv.z) | ((unsigned)f2bf(wv.w) << 16);
    }

    int lane = tid & 63;
    int wv_  = tid >> 6;          // wave 0..3
    int m0   = wv_ << 4;          // node base within tile
    int lr   = lane & 15;
    int lg   = lane >> 4;         // 0..3

    for (int t4 = 0; t4 < 4; ++t4) {
        int tile = blockIdx.x * 4 + t4;
        if (tile >= NB_LIN) break;
        int base = tile * 64;
        int nmax = N_NODES - base; if (nmax > 64) nmax = 64;

        // stage x tile
        #pragma unroll
        for (int rr = 0; rr < 8; ++rr) {
            int idx = rr * 256 + tid;
            int n = idx >> 5, q = idx & 31;
            int d   = (n << 6) + (q << 1);
            int sdw = (n & 7) << 2;
            float4 xv = make_float4(0.f, 0.f, 0.f, 0.f);
            if (n < nmax) xv = *(const float4*)(x + (size_t)(base + n) * F_IN + q * 4);
            xs[(d ^ sdw)]     = (unsigned)f2bf(xv.x) | ((unsigned)f2bf(xv.y) << 16);
            xs[(d ^ sdw) + 1] = (unsigned)f2bf(xv.z) | ((unsigned)f2bf(xv.w) << 16);
        }
        __syncthreads();

        f32x4 acc0 = (f32x4)(0.f), acc1 = (f32x4)(0.f);
        f32x4 acc2 = (f32x4)(0.f), acc3 = (f32x4)(0.f);

        #pragma unroll
        for (int t = 0; t < 4; ++t) {          // k-tiles of 32
            int nn = m0 + lr;
            int da = ((nn << 6) + (t << 4) + (lg << 2)) ^ ((nn & 7) << 2);
            short8 a = *(const short8*)(xs + da);
            #pragma unroll
            for (int ff = 0; ff < 4; ++ff) {   // feature tiles of 16
                int f  = (ff << 4) + lr;
                int db = ((f << 6) + (t << 4) + (lg << 2)) ^ ((f & 7) << 2);
                short8 b = *(const short8*)(ws + db);
                f32x4 c = (ff == 0) ? acc0 : (ff == 1) ? acc1 : (ff == 2) ? acc2 : acc3;
                c = __builtin_amdgcn_mfma_f32_16x16x32_bf16(a, b, c, 0, 0, 0);
                if (ff == 0) acc0 = c; else if (ff == 1) acc1 = c;
                else if (ff == 2) acc2 = c; else acc3 = c;
            }
        }

        // D layout: feat = ff*16 + (lane&15), node = m0 + (lane>>4)*4 + r
        #pragma unroll
        for (int r = 0; r < 4; ++r) {
            int node = m0 + (lg << 2) + r;
            if (node < nmax) {
                size_t o = (size_t)(base + node) * F_OUT + lr;
                z[o +  0] = f2bf(acc0[r]);
                z[o + 16] = f2bf(acc1[r]);
                z[o + 32] = f2bf(acc2[r]);
                z[o + 48] = f2bf(acc3[r]);
            }
        }
        __syncthreads();   // protect xs before next tile's staging
    }
}

// ---------------- exclusive scan of deg -> offs ----------------
__global__ __launch_bounds__(SCAN_BLK) void scan1_k(const int* __restrict__ deg,
                                                    int* __restrict__ offs,
                                                    int* __restrict__ bsum) {
    __shared__ int lds[SCAN_BLK];
    int tid = threadIdx.x;
    int i = blockIdx.x * SCAN_BLK + tid;
    int v = (i < N_NODES) ? deg[i] : 0;
    lds[tid] = v;
    __syncthreads();
    for (int off = 1; off < SCAN_BLK; off <<= 1) {
        int t = (tid >= off) ? lds[tid - off] : 0;
        __syncthreads();
        lds[tid] += t;
        __syncthreads();
    }
    if (i < N_NODES) offs[i] = lds[tid] - v;
    if (tid == SCAN_BLK - 1) bsum[blockIdx.x] = lds[tid];
}

__global__ __launch_bounds__(128) void scan2_k(int* __restrict__ bsum) {
    __shared__ int lds[128];
    int tid = threadIdx.x;
    int v = (tid < N_SBLK) ? bsum[tid] : 0;
    lds[tid] = v;
    __syncthreads();
    for (int off = 1; off < 128; off <<= 1) {
        int t = (tid >= off) ? lds[tid - off] : 0;
        __syncthreads();
        lds[tid] += t;
        __syncthreads();
    }
    if (tid < N_SBLK) bsum[tid] = lds[tid] - v;
}

// scan3 + dis = rsqrt(deg+1) fused
__global__ __launch_bounds__(SCAN_BLK) void scan3_k(int* __restrict__ offs,
                                                    const int* __restrict__ bsum,
                                                    const int* __restrict__ deg,
                                                    float* __restrict__ dis) {
    int i = blockIdx.x * SCAN_BLK + threadIdx.x;
    if (i < N_NODES) {
        offs[i] = offs[i] + bsum[blockIdx.x];
        dis[i] = rsqrtf((float)deg[i] + 1.0f);
    }
}

// ---------------- fused: fill CSR bucket (atomic-free) + y = dis*z (bf16) ----------------
__global__ __launch_bounds__(256) void fill_y_k(const int* __restrict__ row,
                                                const int* __restrict__ col,
                                                const int* __restrict__ offs,
                                                const int* __restrict__ rank,
                                                int* __restrict__ bucket,
                                                const unsigned short* __restrict__ z,
                                                const float* __restrict__ dis,
                                                unsigned short* __restrict__ y) {
    if (blockIdx.x < FILL_B) {
        int t = blockIdx.x * 256 + threadIdx.x;
        #pragma unroll
        for (int u = 0; u < 4; ++u) {
            int e = t + u * FILL_T;
            if (e < N_EDGES) {
                int c = col[e];                       // coalesced
                bucket[offs[c] + rank[e]] = row[e];   // L2 gather + scattered store
            }
        }
        return;
    }
    // y section: 800000 ushort8 chunks (8 bf16 each)
    int t = (blockIdx.x - FILL_B) * 256 + threadIdx.x;
    for (int c = t; c < (N_NODES * F_OUT) / 8; c += YB * 256) {
        ushort8 v = ((const ushort8*)z)[c];
        float d = dis[c >> 3];
        ushort8 o;
        #pragma unroll
        for (int k = 0; k < 8; ++k) o[k] = f2bf(d * bf2f(v[k]));
        ((ushort8*)y)[c] = o;
    }
}

// ---------------- gather_v4: register acc, uniform 8-wide clamped batches ----------------
// Wave handles 8 consecutive nodes; lane = feature. All loads unconditional
// (indices clamped to e-1); contributions zeroed by uniform-predicate cndmask.
// y is pre-scaled (dis folded): the bucket->y chain is the only dependency.
__global__ __launch_bounds__(256) void gather_pool_k(const unsigned short* __restrict__ y,
                                                     const int* __restrict__ offs,
                                                     const int* __restrict__ deg,
                                                     const int* __restrict__ bucket,
                                                     const float* __restrict__ dis,
                                                     const int* __restrict__ batch,
                                                     const float* __restrict__ bias,
                                                     float* __restrict__ psum,
                                                     int* __restrict__ pcnt) {
    int lane = threadIdx.x & 63;
    int wid  = threadIdx.x >> 6;
    int i0   = (blockIdx.x * 4 + wid) * 8;   // 100000 = 3125 * 32
    float bf = bias[lane];

    // prefetch the 8 nodes' metadata lane-parallel, distribute via shfl
    int   om = (lane < 8) ? offs[i0 + lane]  : 0;
    int   dm = (lane < 8) ? deg[i0 + lane]   : 0;
    float sm = (lane < 8) ? dis[i0 + lane]   : 0.f;
    int   gm = (lane < 8) ? batch[i0 + lane] : 0;

    float racc = 0.f;
    int cur = -1, runlen = 0;
    #pragma unroll
    for (int n = 0; n < 8; ++n) {
        int i = i0 + n;
        int s = __shfl(om, n);
        int e = s + __shfl(dm, n);
        float acc = bf2f(y[(size_t)i * F_OUT + lane]);   // self-loop (pre-scaled)

        for (int j = s; j < e; j += 8) {
            // 8 unconditional bucket loads (wave-uniform addrs), clamped to e-1
            int i1 = (j + 1 < e) ? j + 1 : e - 1;
            int i2 = (j + 2 < e) ? j + 2 : e - 1;
            int i3 = (j + 3 < e) ? j + 3 : e - 1;
            int i4 = (j + 4 < e) ? j + 4 : e - 1;
            int i5 = (j + 5 < e) ? j + 5 : e - 1;
            int i6 = (j + 6 < e) ? j + 6 : e - 1;
            int i7 = (j + 7 < e) ? j + 7 : e - 1;
            int r0 = bucket[j],  r1 = bucket[i1], r2 = bucket[i2], r3 = bucket[i3];
            int r4 = bucket[i4], r5 = bucket[i5], r6 = bucket[i6], r7 = bucket[i7];
            float v0 = bf2f(y[(size_t)r0 * F_OUT + lane]);
            float v1 = bf2f(y[(size_t)r1 * F_OUT + lane]);
            float v2 = bf2f(y[(size_t)r2 * F_OUT + lane]);
            float v3 = bf2f(y[(size_t)r3 * F_OUT + lane]);
            float v4 = bf2f(y[(size_t)r4 * F_OUT + lane]);
            float v5 = bf2f(y[(size_t)r5 * F_OUT + lane]);
            float v6 = bf2f(y[(size_t)r6 * F_OUT + lane]);
            float v7 = bf2f(y[(size_t)r7 * F_OUT + lane]);
            acc += v0;                                   // j < e by loop cond
            acc += (j + 1 < e) ? v1 : 0.f;
            acc += (j + 2 < e) ? v2 : 0.f;
            acc += (j + 3 < e) ? v3 : 0.f;
            acc += (j + 4 < e) ? v4 : 0.f;
            acc += (j + 5 < e) ? v5 : 0.f;
            acc += (j + 6 < e) ? v6 : 0.f;
            acc += (j + 7 < e) ? v7 : 0.f;
        }

        float di = __shfl(sm, n);
        float v = fmaxf(fmaf(di, acc, bf), 0.f);
        int g = __shfl(gm, n);
        if (g != cur) {
            if (cur >= 0) {
                atomicAdd(&psum[cur * F_OUT + lane], racc);
                if (lane == 0) atomicAdd(&pcnt[cur], runlen);
            }
            cur = g; racc = 0.f; runlen = 0;
        }
        racc += v; runlen++;
    }
    if (cur >= 0) {
        atomicAdd(&psum[cur * F_OUT + lane], racc);
        if (lane == 0) atomicAdd(&pcnt[cur], runlen);
    }
}

// ---------------- out = psum / max(count,1) ----------------
__global__ __launch_bounds__(256) void final_k(const float* __restrict__ psum,
                                               const int* __restrict__ pcnt,
                                               float* __restrict__ out) {
    int t = blockIdx.x * blockDim.x + threadIdx.x;
    if (t < N_GRAPHS * F_OUT) {
        int g = t >> 6;
        float c = (float)(pcnt[g] > 1 ? pcnt[g] : 1);
        out[t] = psum[t] / c;
    }
}

extern "C" void kernel_launch(void* const* d_in, const int* in_sizes, int n_in,
                              void* d_out, int out_size, void* d_ws, size_t ws_size,
                              hipStream_t stream) {
    const float* node_feat = (const float*)d_in[0];
    const int*   edges     = (const int*)d_in[1];   // [2, E] flat: row then col
    const int*   batch     = (const int*)d_in[2];
    const float* W         = (const float*)d_in[3];
    const float* b         = (const float*)d_in[4];

    // workspace carve-up (~38 MB)
    unsigned short* z = (unsigned short*)d_ws;              // N*64 bf16
    int*   deg    = (int*)(z + (size_t)N_NODES * F_OUT);    // N
    float* psum   = (float*)(deg + N_NODES);                // G*64
    int*   pcnt   = (int*)(psum + N_GRAPHS * F_OUT);        // G
    float* dis    = (float*)(pcnt + N_GRAPHS);              // N
    int*   offs   = (int*)(dis + N_NODES);                  // N
    int*   bsum   = offs + N_NODES;                         // 128
    int*   bucket = bsum + 128;                             // E
    int*   rank   = bucket + N_EDGES;                       // E
    unsigned short* y = (unsigned short*)(rank + N_EDGES);  // N*64 bf16

    // zero deg + psum + pcnt (contiguous)
    size_t zbytes = ((size_t)N_NODES + N_GRAPHS * F_OUT + N_GRAPHS) * 4;
    hipMemsetAsync(deg, 0, zbytes, stream);

    const int* row = edges;
    const int* col = edges + N_EDGES;

    lin_deg_k<<<NB_LINB + NB_DEG, 256, 0, stream>>>(node_feat, W, z, col, deg, rank);
    scan1_k<<<N_SBLK, SCAN_BLK, 0, stream>>>(deg, offs, bsum);
    scan2_k<<<1, 128, 0, stream>>>(bsum);
    scan3_k<<<N_SBLK, SCAN_BLK, 0, stream>>>(offs, bsum, deg, dis);
    fill_y_k<<<FILL_B + YB, 256, 0, stream>>>(row, col, offs, rank, bucket, z, dis, y);
    gather_pool_k<<<N_NODES / 32, 256, 0, stream>>>(y, offs, deg, bucket,
                                                    dis, batch, b, psum, pcnt);
    final_k<<<(N_GRAPHS * F_OUT + 255) / 256, 256, 0, stream>>>(psum, pcnt, (float*)d_out);
}

// Round 11
// 155.691 us; speedup vs baseline: 3.7190x; 1.0344x over previous
//
#include <hip/hip_runtime.h>

#define N_NODES  100000
#define N_EDGES  1250000
#define F_IN     128
#define F_OUT    64
#define N_GRAPHS 256
#define SCAN_BLK 1024
#define N_SBLK   98
#define NB_LIN   1563          // total 64-node tiles
#define NB_LINB  391           // MFMA blocks; 4 tiles each, W staged once
#define NB_DEG   1221          // deg/rank section: 4 edges per thread
#define FILL_B   1221          // 4 edges/thread scatter section
#define FILL_T   (FILL_B * 256)
#define YB       1024          // y = dis*z section blocks

typedef __attribute__((ext_vector_type(8))) short short8;   // 8 bf16 (4 VGPRs)
typedef __attribute__((ext_vector_type(8))) unsigned short ushort8;
typedef __attribute__((ext_vector_type(4))) float f32x4;

static __device__ __forceinline__ unsigned short f2bf(float f) {
    unsigned u = __builtin_bit_cast(unsigned, f);
    u += 0x7fff + ((u >> 16) & 1);            // RNE
    return (unsigned short)(u >> 16);
}
static __device__ __forceinline__ float bf2f(unsigned short h) {
    unsigned u = ((unsigned)h) << 16;
    return __builtin_bit_cast(float, u);
}
static __device__ __forceinline__ float bflo(unsigned v) {   // low bf16 of packed u32
    return __builtin_bit_cast(float, v << 16);
}
static __device__ __forceinline__ float bfhi(unsigned v) {   // high bf16 of packed u32
    return __builtin_bit_cast(float, v & 0xffff0000u);
}

// ---------------- fused: MFMA linear (z = x@W^T, bf16) + degree/rank count ----------------
// Blocks [0, NB_LINB): 4 node-tiles each, W staged once. Blocks [NB_LINB, ...):
// rank[e] = atomicAdd(&deg[col[e]], 1), 4 independent atomics/thread.
__global__ __launch_bounds__(256) void lin_deg_k(const float* __restrict__ x,
                                                 const float* __restrict__ W,
                                                 unsigned short* __restrict__ z,
                                                 const int* __restrict__ col,
                                                 int* __restrict__ deg,
                                                 int* __restrict__ rank) {
    if (blockIdx.x >= NB_LINB) {
        int t = (blockIdx.x - NB_LINB) * 256 + threadIdx.x;
        int e0 = t, e1 = t + FILL_T, e2 = t + 2 * FILL_T, e3 = t + 3 * FILL_T;
        bool v3 = e3 < N_EDGES;
        int c0 = col[e0], c1 = col[e1], c2 = col[e2];
        int c3 = v3 ? col[e3] : 0;
        int p0 = atomicAdd(&deg[c0], 1);          // 4 independent atomics in flight
        int p1 = atomicAdd(&deg[c1], 1);
        int p2 = atomicAdd(&deg[c2], 1);
        int p3 = v3 ? atomicAdd(&deg[c3], 1) : 0;
        rank[e0] = p0;                            // coalesced stores
        rank[e1] = p1;
        rank[e2] = p2;
        if (v3) rank[e3] = p3;
        return;
    }

    __shared__ unsigned xs[64 * 64];   // 16 KB: 64 nodes x 128 k (bf16 pairs)
    __shared__ unsigned ws[64 * 64];   // 16 KB: 64 feats x 128 k
    int tid  = threadIdx.x;

    // stage W ONCE (re-used across 4 tiles)
    #pragma unroll
    for (int rr = 0; rr < 8; ++rr) {
        int idx = rr * 256 + tid;          // 0..2047
        int n = idx >> 5, q = idx & 31;
        int d   = (n << 6) + (q << 1);
        int sdw = (n & 7) << 2;
        const float4 wv = *(const float4*)(W + (size_t)n * F_IN + q * 4);
        ws[(d ^ sdw)]     = (unsigned)f2bf(wv.x) | ((unsigned)f2bf(wv.y) << 16);
        ws[(d ^ sdw) + 1] = (unsigned)f2bf(wv.z) | ((unsigned)f2bf(wv.w) << 16);
    }

    int lane = tid & 63;
    int wv_  = tid >> 6;          // wave 0..3
    int m0   = wv_ << 4;          // node base within tile
    int lr   = lane & 15;
    int lg   = lane >> 4;         // 0..3

    for (int t4 = 0; t4 < 4; ++t4) {
        int tile = blockIdx.x * 4 + t4;
        if (tile >= NB_LIN) break;
        int base = tile * 64;
        int nmax = N_NODES - base; if (nmax > 64) nmax = 64;

        // stage x tile
        #pragma unroll
        for (int rr = 0; rr < 8; ++rr) {
            int idx = rr * 256 + tid;
            int n = idx >> 5, q = idx & 31;
            int d   = (n << 6) + (q << 1);
            int sdw = (n & 7) << 2;
            float4 xv = make_float4(0.f, 0.f, 0.f, 0.f);
            if (n < nmax) xv = *(const float4*)(x + (size_t)(base + n) * F_IN + q * 4);
            xs[(d ^ sdw)]     = (unsigned)f2bf(xv.x) | ((unsigned)f2bf(xv.y) << 16);
            xs[(d ^ sdw) + 1] = (unsigned)f2bf(xv.z) | ((unsigned)f2bf(xv.w) << 16);
        }
        __syncthreads();

        f32x4 acc0 = (f32x4)(0.f), acc1 = (f32x4)(0.f);
        f32x4 acc2 = (f32x4)(0.f), acc3 = (f32x4)(0.f);

        #pragma unroll
        for (int t = 0; t < 4; ++t) {          // k-tiles of 32
            int nn = m0 + lr;
            int da = ((nn << 6) + (t << 4) + (lg << 2)) ^ ((nn & 7) << 2);
            short8 a = *(const short8*)(xs + da);
            #pragma unroll
            for (int ff = 0; ff < 4; ++ff) {   // feature tiles of 16
                int f  = (ff << 4) + lr;
                int db = ((f << 6) + (t << 4) + (lg << 2)) ^ ((f & 7) << 2);
                short8 b = *(const short8*)(ws + db);
                f32x4 c = (ff == 0) ? acc0 : (ff == 1) ? acc1 : (ff == 2) ? acc2 : acc3;
                c = __builtin_amdgcn_mfma_f32_16x16x32_bf16(a, b, c, 0, 0, 0);
                if (ff == 0) acc0 = c; else if (ff == 1) acc1 = c;
                else if (ff == 2) acc2 = c; else acc3 = c;
            }
        }

        // D layout: feat = ff*16 + (lane&15), node = m0 + (lane>>4)*4 + r
        #pragma unroll
        for (int r = 0; r < 4; ++r) {
            int node = m0 + (lg << 2) + r;
            if (node < nmax) {
                size_t o = (size_t)(base + node) * F_OUT + lr;
                z[o +  0] = f2bf(acc0[r]);
                z[o + 16] = f2bf(acc1[r]);
                z[o + 32] = f2bf(acc2[r]);
                z[o + 48] = f2bf(acc3[r]);
            }
        }
        __syncthreads();   // protect xs before next tile's staging
    }
}

// ---------------- exclusive scan of deg -> offs ----------------
__global__ __launch_bounds__(SCAN_BLK) void scan1_k(const int* __restrict__ deg,
                                                    int* __restrict__ offs,
                                                    int* __restrict__ bsum) {
    __shared__ int lds[SCAN_BLK];
    int tid = threadIdx.x;
    int i = blockIdx.x * SCAN_BLK + tid;
    int v = (i < N_NODES) ? deg[i] : 0;
    lds[tid] = v;
    __syncthreads();
    for (int off = 1; off < SCAN_BLK; off <<= 1) {
        int t = (tid >= off) ? lds[tid - off] : 0;
        __syncthreads();
        lds[tid] += t;
        __syncthreads();
    }
    if (i < N_NODES) offs[i] = lds[tid] - v;
    if (tid == SCAN_BLK - 1) bsum[blockIdx.x] = lds[tid];
}

__global__ __launch_bounds__(128) void scan2_k(int* __restrict__ bsum) {
    __shared__ int lds[128];
    int tid = threadIdx.x;
    int v = (tid < N_SBLK) ? bsum[tid] : 0;
    lds[tid] = v;
    __syncthreads();
    for (int off = 1; off < 128; off <<= 1) {
        int t = (tid >= off) ? lds[tid - off] : 0;
        __syncthreads();
        lds[tid] += t;
        __syncthreads();
    }
    if (tid < N_SBLK) bsum[tid] = lds[tid] - v;
}

// scan3 + dis = rsqrt(deg+1) fused
__global__ __launch_bounds__(SCAN_BLK) void scan3_k(int* __restrict__ offs,
                                                    const int* __restrict__ bsum,
                                                    const int* __restrict__ deg,
                                                    float* __restrict__ dis) {
    int i = blockIdx.x * SCAN_BLK + threadIdx.x;
    if (i < N_NODES) {
        offs[i] = offs[i] + bsum[blockIdx.x];
        dis[i] = rsqrtf((float)deg[i] + 1.0f);
    }
}

// ---------------- fused: fill CSR bucket (atomic-free) + y = dis*z (bf16) ----------------
__global__ __launch_bounds__(256) void fill_y_k(const int* __restrict__ row,
                                                const int* __restrict__ col,
                                                const int* __restrict__ offs,
                                                const int* __restrict__ rank,
                                                int* __restrict__ bucket,
                                                const unsigned short* __restrict__ z,
                                                const float* __restrict__ dis,
                                                unsigned short* __restrict__ y) {
    if (blockIdx.x < FILL_B) {
        int t = blockIdx.x * 256 + threadIdx.x;
        #pragma unroll
        for (int u = 0; u < 4; ++u) {
            int e = t + u * FILL_T;
            if (e < N_EDGES) {
                int c = col[e];                       // coalesced
                bucket[offs[c] + rank[e]] = row[e];   // L2 gather + scattered store
            }
        }
        return;
    }
    // y section: 800000 ushort8 chunks (8 bf16 each)
    int t = (blockIdx.x - FILL_B) * 256 + threadIdx.x;
    for (int c = t; c < (N_NODES * F_OUT) / 8; c += YB * 256) {
        ushort8 v = ((const ushort8*)z)[c];
        float d = dis[c >> 3];
        ushort8 o;
        #pragma unroll
        for (int k = 0; k < 8; ++k) o[k] = f2bf(d * bf2f(v[k]));
        ((ushort8*)y)[c] = o;
    }
}

// ---------------- gather_v5: half-wave edge pairing + clamped unconditional loads ----
// Wave handles 8 consecutive nodes. lane = (eo = lane>>5 edge slot, fp = lane&31
// feature pair u32). Per wave-instruction: 2 edges. 8-deep unroll -> 16 edges in
// flight. All loads unconditional (clamped to e-1); adds predicated by per-lane
// cndmask (no branches). y pre-scaled: bucket->y is the only dependent chain.
__global__ __launch_bounds__(256) void gather_pool_k(const unsigned short* __restrict__ y,
                                                     const int* __restrict__ offs,
                                                     const int* __restrict__ deg,
                                                     const int* __restrict__ bucket,
                                                     const float* __restrict__ dis,
                                                     const int* __restrict__ batch,
                                                     const float* __restrict__ bias,
                                                     float* __restrict__ psum,
                                                     int* __restrict__ pcnt) {
    int lane = threadIdx.x & 63;
    int wid  = threadIdx.x >> 6;
    int i0   = (blockIdx.x * 4 + wid) * 8;   // 100000 = 3125 * 32
    int eo   = lane >> 5;                    // edge slot 0/1
    int fp   = lane & 31;                    // feature pair: feats 2fp, 2fp+1
    float bx = bias[2 * fp], by = bias[2 * fp + 1];

    // prefetch the 8 nodes' metadata lane-parallel, distribute via shfl
    int   om = (lane < 8) ? offs[i0 + lane]  : 0;
    int   dm = (lane < 8) ? deg[i0 + lane]   : 0;
    float sm = (lane < 8) ? dis[i0 + lane]   : 0.f;
    int   gm = (lane < 8) ? batch[i0 + lane] : 0;

    float rx = 0.f, ry = 0.f;                // pool run accumulator
    int cur = -1, runlen = 0;
    #pragma unroll
    for (int n = 0; n < 8; ++n) {
        int i = i0 + n;
        int s = __shfl(om, n);
        int e = s + __shfl(dm, n);

        // self-loop term (pre-scaled y), counted in slot 0 only
        unsigned sv = *(const unsigned*)(y + (size_t)i * F_OUT + 2 * fp);
        float ax = (eo == 0) ? bflo(sv) : 0.f;
        float ay = (eo == 0) ? bfhi(sv) : 0.f;

        for (int j = s; j < e; j += 16) {
            #pragma unroll
            for (int u = 0; u < 8; ++u) {
                int id  = j + 2 * u + eo;
                int idc = (id < e) ? id : e - 1;          // clamp: load unconditional
                int r   = bucket[idc];
                unsigned w = *(const unsigned*)(y + (size_t)r * F_OUT + 2 * fp);
                float wx = bflo(w), wy = bfhi(w);
                ax += (id < e) ? wx : 0.f;                // per-lane cndmask, no branch
                ay += (id < e) ? wy : 0.f;
            }
        }
        // combine the two edge slots (both halves end with the full sum)
        ax += __shfl_xor(ax, 32);
        ay += __shfl_xor(ay, 32);

        float di = __shfl(sm, n);
        float vx = fmaxf(fmaf(di, ax, bx), 0.f);
        float vy = fmaxf(fmaf(di, ay, by), 0.f);
        int g = __shfl(gm, n);
        if (g != cur) {
            if (cur >= 0 && eo == 0) {
                atomicAdd(&psum[cur * F_OUT + 2 * fp],     rx);
                atomicAdd(&psum[cur * F_OUT + 2 * fp + 1], ry);
                if (lane == 0) atomicAdd(&pcnt[cur], runlen);
            }
            cur = g; rx = 0.f; ry = 0.f; runlen = 0;
        }
        rx += vx; ry += vy; runlen++;
    }
    if (cur >= 0 && eo == 0) {
        atomicAdd(&psum[cur * F_OUT + 2 * fp],     rx);
        atomicAdd(&psum[cur * F_OUT + 2 * fp + 1], ry);
        if (lane == 0) atomicAdd(&pcnt[cur], runlen);
    }
}

// ---------------- out = psum / max(count,1) ----------------
__global__ __launch_bounds__(256) void final_k(const float* __restrict__ psum,
                                               const int* __restrict__ pcnt,
                                               float* __restrict__ out) {
    int t = blockIdx.x * blockDim.x + threadIdx.x;
    if (t < N_GRAPHS * F_OUT) {
        int g = t >> 6;
        float c = (float)(pcnt[g] > 1 ? pcnt[g] : 1);
        out[t] = psum[t] / c;
    }
}

extern "C" void kernel_launch(void* const* d_in, const int* in_sizes, int n_in,
                              void* d_out, int out_size, void* d_ws, size_t ws_size,
                              hipStream_t stream) {
    const float* node_feat = (const float*)d_in[0];
    const int*   edges     = (const int*)d_in[1];   // [2, E] flat: row then col
    const int*   batch     = (const int*)d_in[2];
    const float* W         = (const float*)d_in[3];
    const float* b         = (const float*)d_in[4];

    // workspace carve-up (~38 MB)
    unsigned short* z = (unsigned short*)d_ws;              // N*64 bf16
    int*   deg    = (int*)(z + (size_t)N_NODES * F_OUT);    // N
    float* psum   = (float*)(deg + N_NODES);                // G*64
    int*   pcnt   = (int*)(psum + N_GRAPHS * F_OUT);        // G
    float* dis    = (float*)(pcnt + N_GRAPHS);              // N
    int*   offs   = (int*)(dis + N_NODES);                  // N
    int*   bsum   = offs + N_NODES;                         // 128
    int*   bucket = bsum + 128;                             // E
    int*   rank   = bucket + N_EDGES;                       // E
    unsigned short* y = (unsigned short*)(rank + N_EDGES);  // N*64 bf16

    // zero deg + psum + pcnt (contiguous)
    size_t zbytes = ((size_t)N_NODES + N_GRAPHS * F_OUT + N_GRAPHS) * 4;
    hipMemsetAsync(deg, 0, zbytes, stream);

    const int* row = edges;
    const int* col = edges + N_EDGES;

    lin_deg_k<<<NB_LINB + NB_DEG, 256, 0, stream>>>(node_feat, W, z, col, deg, rank);
    scan1_k<<<N_SBLK, SCAN_BLK, 0, stream>>>(deg, offs, bsum);
    scan2_k<<<1, 128, 0, stream>>>(bsum);
    scan3_k<<<N_SBLK, SCAN_BLK, 0, stream>>>(offs, bsum, deg, dis);
    fill_y_k<<<FILL_B + YB, 256, 0, stream>>>(row, col, offs, rank, bucket, z, dis, y);
    gather_pool_k<<<N_NODES / 32, 256, 0, stream>>>(y, offs, deg, bucket,
                                                    dis, batch, b, psum, pcnt);
    final_k<<<(N_GRAPHS * F_OUT + 255) / 256, 256, 0, stream>>>(psum, pcnt, (float*)d_out);
}

// Round 12
// 119.207 us; speedup vs baseline: 4.8572x; 1.3061x over previous
//
#include <hip/hip_runtime.h>

#define N_NODES  100000
#define N_EDGES  1250000
#define F_IN     128
#define F_OUT    64
#define N_GRAPHS 256
#define NB_LIN   1563          // total 64-node linear tiles
#define NB_LINB  391           // MFMA blocks; 4 tiles each, W staged once
#define NBKT     782           // coarse buckets: col>>7 (128 nodes each)
#define NCHK     256           // edge chunks
#define CHKSZ    4883          // ceil(E/NCHK); 256*4883 = 1250048
#define M_H      (NBKT * NCHK) // 200192 histogram cells
#define MB_H     196           // ceil(M_H/1024)
#define BKT_CAP  2048          // max edges per bucket (mean 1600, sigma 40)

typedef __attribute__((ext_vector_type(8))) short short8;   // 8 bf16 (4 VGPRs)
typedef __attribute__((ext_vector_type(4))) float f32x4;

static __device__ __forceinline__ unsigned short f2bf(float f) {
    unsigned u = __builtin_bit_cast(unsigned, f);
    u += 0x7fff + ((u >> 16) & 1);            // RNE
    return (unsigned short)(u >> 16);
}
static __device__ __forceinline__ float bf2f(unsigned short h) {
    unsigned u = ((unsigned)h) << 16;
    return __builtin_bit_cast(float, u);
}
static __device__ __forceinline__ float bflo(unsigned v) {   // low bf16 of packed u32
    return __builtin_bit_cast(float, v << 16);
}
static __device__ __forceinline__ float bfhi(unsigned v) {   // high bf16 of packed u32
    return __builtin_bit_cast(float, v & 0xffff0000u);
}

// ---------------- fused: MFMA linear (z = x@W^T, bf16) + chunk histograms ----------------
// Blocks [0, NB_LINB): linear, 4 node-tiles each. Blocks [NB_LINB, NB_LINB+NCHK):
// chunk c histograms its 4883 edges' col>>7 into LDS (782 counters), writes H[b][c].
// NO global atomics anywhere.
__global__ __launch_bounds__(256) void lin_hist_k(const float* __restrict__ x,
                                                  const float* __restrict__ W,
                                                  unsigned short* __restrict__ z,
                                                  const int* __restrict__ col,
                                                  int* __restrict__ H) {
    __shared__ unsigned xs[64 * 64];   // 16 KB (hist path reuses as counters)
    __shared__ unsigned ws[64 * 64];   // 16 KB
    int tid = threadIdx.x;

    if (blockIdx.x >= NB_LINB) {
        int c = blockIdx.x - NB_LINB;          // chunk id
        int* cnt = (int*)xs;                   // 782 counters overlay
        for (int b = tid; b < NBKT; b += 256) cnt[b] = 0;
        __syncthreads();
        int s = c * CHKSZ;
        int e = s + CHKSZ; if (e > N_EDGES) e = N_EDGES;
        for (int i = s + tid; i < e; i += 256)
            atomicAdd(&cnt[col[i] >> 7], 1);   // LDS atomic: ~1 lane-op/edge
        __syncthreads();
        for (int b = tid; b < NBKT; b += 256)
            H[b * NCHK + c] = cnt[b];
        return;
    }

    // ---- linear section (unchanged from r10) ----
    #pragma unroll
    for (int rr = 0; rr < 8; ++rr) {
        int idx = rr * 256 + tid;
        int n = idx >> 5, q = idx & 31;
        int d   = (n << 6) + (q << 1);
        int sdw = (n & 7) << 2;
        const float4 wv = *(const float4*)(W + (size_t)n * F_IN + q * 4);
        ws[(d ^ sdw)]     = (unsigned)f2bf(wv.x) | ((unsigned)f2bf(wv.y) << 16);
        ws[(d ^ sdw) + 1] = (unsigned)f2bf(wv.z) | ((unsigned)f2bf(wv.w) << 16);
    }

    int lane = tid & 63;
    int wv_  = tid >> 6;
    int m0   = wv_ << 4;
    int lr   = lane & 15;
    int lg   = lane >> 4;

    for (int t4 = 0; t4 < 4; ++t4) {
        int tile = blockIdx.x * 4 + t4;
        if (tile >= NB_LIN) break;
        int base = tile * 64;
        int nmax = N_NODES - base; if (nmax > 64) nmax = 64;

        #pragma unroll
        for (int rr = 0; rr < 8; ++rr) {
            int idx = rr * 256 + tid;
            int n = idx >> 5, q = idx & 31;
            int d   = (n << 6) + (q << 1);
            int sdw = (n & 7) << 2;
            float4 xv = make_float4(0.f, 0.f, 0.f, 0.f);
            if (n < nmax) xv = *(const float4*)(x + (size_t)(base + n) * F_IN + q * 4);
            xs[(d ^ sdw)]     = (unsigned)f2bf(xv.x) | ((unsigned)f2bf(xv.y) << 16);
            xs[(d ^ sdw) + 1] = (unsigned)f2bf(xv.z) | ((unsigned)f2bf(xv.w) << 16);
        }
        __syncthreads();

        f32x4 acc0 = (f32x4)(0.f), acc1 = (f32x4)(0.f);
        f32x4 acc2 = (f32x4)(0.f), acc3 = (f32x4)(0.f);

        #pragma unroll
        for (int t = 0; t < 4; ++t) {
            int nn = m0 + lr;
            int da = ((nn << 6) + (t << 4) + (lg << 2)) ^ ((nn & 7) << 2);
            short8 a = *(const short8*)(xs + da);
            #pragma unroll
            for (int ff = 0; ff < 4; ++ff) {
                int f  = (ff << 4) + lr;
                int db = ((f << 6) + (t << 4) + (lg << 2)) ^ ((f & 7) << 2);
                short8 b = *(const short8*)(ws + db);
                f32x4 c = (ff == 0) ? acc0 : (ff == 1) ? acc1 : (ff == 2) ? acc2 : acc3;
                c = __builtin_amdgcn_mfma_f32_16x16x32_bf16(a, b, c, 0, 0, 0);
                if (ff == 0) acc0 = c; else if (ff == 1) acc1 = c;
                else if (ff == 2) acc2 = c; else acc3 = c;
            }
        }

        #pragma unroll
        for (int r = 0; r < 4; ++r) {
            int node = m0 + (lg << 2) + r;
            if (node < nmax) {
                size_t o = (size_t)(base + node) * F_OUT + lr;
                z[o +  0] = f2bf(acc0[r]);
                z[o + 16] = f2bf(acc1[r]);
                z[o + 32] = f2bf(acc2[r]);
                z[o + 48] = f2bf(acc3[r]);
            }
        }
        __syncthreads();
    }
}

// ---------------- exclusive scan of H (M_H cells, lexicographic (bucket, chunk)) ----------
__global__ __launch_bounds__(1024) void scanH1_k(int* __restrict__ H, int* __restrict__ bsum) {
    __shared__ int lds[1024];
    int tid = threadIdx.x;
    int i = blockIdx.x * 1024 + tid;
    int v = (i < M_H) ? H[i] : 0;
    lds[tid] = v;
    __syncthreads();
    for (int off = 1; off < 1024; off <<= 1) {
        int t = (tid >= off) ? lds[tid - off] : 0;
        __syncthreads();
        lds[tid] += t;
        __syncthreads();
    }
    if (i < M_H) H[i] = lds[tid] - v;
    if (tid == 1023) bsum[blockIdx.x] = lds[tid];
}

__global__ __launch_bounds__(256) void scanH2_k(int* __restrict__ bsum) {
    __shared__ int lds[256];
    int tid = threadIdx.x;
    int v = (tid < MB_H) ? bsum[tid] : 0;
    lds[tid] = v;
    __syncthreads();
    for (int off = 1; off < 256; off <<= 1) {
        int t = (tid >= off) ? lds[tid - off] : 0;
        __syncthreads();
        lds[tid] += t;
        __syncthreads();
    }
    if (tid < MB_H) bsum[tid] = lds[tid] - v;
}

__global__ __launch_bounds__(1024) void scanH3_k(int* __restrict__ H, const int* __restrict__ bsum) {
    int i = blockIdx.x * 1024 + threadIdx.x;
    if (i < M_H) H[i] += bsum[blockIdx.x];
}

// ---------------- scatter: partition edges into coarse buckets (LDS cursors) -----------
__global__ __launch_bounds__(256) void scatter_k(const int* __restrict__ row,
                                                 const int* __restrict__ col,
                                                 const int* __restrict__ Hs,
                                                 int2* __restrict__ part) {
    __shared__ int cur[NBKT];
    int c = blockIdx.x, tid = threadIdx.x;
    for (int b = tid; b < NBKT; b += 256) cur[b] = Hs[b * NCHK + c];
    __syncthreads();
    int s = c * CHKSZ;
    int e = s + CHKSZ; if (e > N_EDGES) e = N_EDGES;
    for (int i = s + tid; i < e; i += 256) {
        int cc = col[i], rr = row[i];
        int p = atomicAdd(&cur[cc >> 7], 1);          // LDS atomic w/ return
        part[p] = make_int2(rr, cc);
    }
}

// ---------------- per-bucket CSR finalize: deg/offs/dis + place rows + scale z --------
__global__ __launch_bounds__(256) void csr_k(const int* __restrict__ Hs,
                                             const int2* __restrict__ part,
                                             int* __restrict__ bucketF,
                                             int* __restrict__ deg,
                                             int* __restrict__ offs,
                                             float* __restrict__ dis,
                                             unsigned* __restrict__ z32) {
    __shared__ int rowL[BKT_CAP];
    __shared__ int colL[BKT_CAP];
    __shared__ int cnt[128], offsL[128], curL[128], scanT[128];
    __shared__ float disL[128];
    int b = blockIdx.x, tid = threadIdx.x;
    int s = Hs[b * NCHK];
    int e = (b < NBKT - 1) ? Hs[(b + 1) * NCHK] : N_EDGES;
    int m = e - s;                                    // <= BKT_CAP (11-sigma)

    if (tid < 128) cnt[tid] = 0;
    __syncthreads();
    for (int i = tid; i < m; i += 256) {
        int2 pr = part[s + i];
        rowL[i] = pr.x;
        int cl = pr.y & 127;
        colL[i] = cl;
        atomicAdd(&cnt[cl], 1);
    }
    __syncthreads();
    // exclusive scan of cnt[0..127] (Hillis-Steele; uniform barriers)
    if (tid < 128) scanT[tid] = cnt[tid];
    __syncthreads();
    for (int off = 1; off < 128; off <<= 1) {
        int v = (tid < 128 && tid >= off) ? scanT[tid - off] : 0;
        __syncthreads();
        if (tid < 128) scanT[tid] += v;
        __syncthreads();
    }
    if (tid < 128) {
        int ex = scanT[tid] - cnt[tid];
        offsL[tid] = ex;
        curL[tid]  = ex;
        float d = rsqrtf((float)cnt[tid] + 1.0f);
        disL[tid] = d;
        int node = b * 128 + tid;
        if (node < N_NODES) {
            deg[node]  = cnt[tid];
            offs[node] = s + ex;
            dis[node]  = d;
        }
    }
    __syncthreads();
    // place rows into final CSR order
    for (int i = tid; i < m; i += 256) {
        int cl = colL[i];
        int p = atomicAdd(&curL[cl], 1);
        bucketF[s + p] = rowL[i];
    }
    // scale z in place: y = dis * z. node = tid>>1, half row (16 u32 = 32 bf16) each
    int node = tid >> 1, half = tid & 1;
    int gnode = b * 128 + node;
    if (gnode < N_NODES) {
        float d = disL[node];
        unsigned* zp = z32 + (size_t)gnode * 32 + half * 16;
        #pragma unroll
        for (int k = 0; k < 16; ++k) {
            unsigned v = zp[k];
            zp[k] = (unsigned)f2bf(d * bflo(v)) | ((unsigned)f2bf(d * bfhi(v)) << 16);
        }
    }
}

// ---------------- gather_v5 (unchanged): half-wave edge pairing, clamped loads --------
__global__ __launch_bounds__(256) void gather_pool_k(const unsigned short* __restrict__ y,
                                                     const int* __restrict__ offs,
                                                     const int* __restrict__ deg,
                                                     const int* __restrict__ bucket,
                                                     const float* __restrict__ dis,
                                                     const int* __restrict__ batch,
                                                     const float* __restrict__ bias,
                                                     float* __restrict__ psum,
                                                     int* __restrict__ pcnt) {
    int lane = threadIdx.x & 63;
    int wid  = threadIdx.x >> 6;
    int i0   = (blockIdx.x * 4 + wid) * 8;   // 100000 = 3125 * 32
    int eo   = lane >> 5;                    // edge slot 0/1
    int fp   = lane & 31;                    // feature pair: feats 2fp, 2fp+1
    float bx = bias[2 * fp], by = bias[2 * fp + 1];

    int   om = (lane < 8) ? offs[i0 + lane]  : 0;
    int   dm = (lane < 8) ? deg[i0 + lane]   : 0;
    float sm = (lane < 8) ? dis[i0 + lane]   : 0.f;
    int   gm = (lane < 8) ? batch[i0 + lane] : 0;

    float rx = 0.f, ry = 0.f;
    int cur = -1, runlen = 0;
    #pragma unroll
    for (int n = 0; n < 8; ++n) {
        int i = i0 + n;
        int s = __shfl(om, n);
        int e = s + __shfl(dm, n);

        unsigned sv = *(const unsigned*)(y + (size_t)i * F_OUT + 2 * fp);
        float ax = (eo == 0) ? bflo(sv) : 0.f;
        float ay = (eo == 0) ? bfhi(sv) : 0.f;

        for (int j = s; j < e; j += 16) {
            #pragma unroll
            for (int u = 0; u < 8; ++u) {
                int id  = j + 2 * u + eo;
                int idc = (id < e) ? id : e - 1;
                int r   = bucket[idc];
                unsigned w = *(const unsigned*)(y + (size_t)r * F_OUT + 2 * fp);
                float wx = bflo(w), wy = bfhi(w);
                ax += (id < e) ? wx : 0.f;
                ay += (id < e) ? wy : 0.f;
            }
        }
        ax += __shfl_xor(ax, 32);
        ay += __shfl_xor(ay, 32);

        float di = __shfl(sm, n);
        float vx = fmaxf(fmaf(di, ax, bx), 0.f);
        float vy = fmaxf(fmaf(di, ay, by), 0.f);
        int g = __shfl(gm, n);
        if (g != cur) {
            if (cur >= 0 && eo == 0) {
                atomicAdd(&psum[cur * F_OUT + 2 * fp],     rx);
                atomicAdd(&psum[cur * F_OUT + 2 * fp + 1], ry);
                if (lane == 0) atomicAdd(&pcnt[cur], runlen);
            }
            cur = g; rx = 0.f; ry = 0.f; runlen = 0;
        }
        rx += vx; ry += vy; runlen++;
    }
    if (cur >= 0 && eo == 0) {
        atomicAdd(&psum[cur * F_OUT + 2 * fp],     rx);
        atomicAdd(&psum[cur * F_OUT + 2 * fp + 1], ry);
        if (lane == 0) atomicAdd(&pcnt[cur], runlen);
    }
}

// ---------------- out = psum / max(count,1) ----------------
__global__ __launch_bounds__(256) void final_k(const float* __restrict__ psum,
                                               const int* __restrict__ pcnt,
                                               float* __restrict__ out) {
    int t = blockIdx.x * blockDim.x + threadIdx.x;
    if (t < N_GRAPHS * F_OUT) {
        int g = t >> 6;
        float c = (float)(pcnt[g] > 1 ? pcnt[g] : 1);
        out[t] = psum[t] / c;
    }
}

extern "C" void kernel_launch(void* const* d_in, const int* in_sizes, int n_in,
                              void* d_out, int out_size, void* d_ws, size_t ws_size,
                              hipStream_t stream) {
    const float* node_feat = (const float*)d_in[0];
    const int*   edges     = (const int*)d_in[1];   // [2, E] flat: row then col
    const int*   batch     = (const int*)d_in[2];
    const float* W         = (const float*)d_in[3];
    const float* b         = (const float*)d_in[4];

    // workspace carve-up (~30 MB)
    unsigned short* z = (unsigned short*)d_ws;               // N*64 bf16 (scaled in place)
    int2*  part    = (int2*)(z + (size_t)N_NODES * F_OUT);   // E pairs (10 MB)
    int*   bucketF = (int*)(part + N_EDGES);                 // E (5 MB)
    int*   H       = bucketF + N_EDGES;                      // M_H
    int*   bsumH   = H + M_H;                                // 256
    int*   deg     = bsumH + 256;                            // N
    int*   offs    = deg + N_NODES;                          // N
    float* dis     = (float*)(offs + N_NODES);               // N
    float* psum    = dis + N_NODES;                          // G*64
    int*   pcnt    = (int*)(psum + N_GRAPHS * F_OUT);        // G

    // zero psum + pcnt only (deg/offs/dis fully written by csr_k)
    hipMemsetAsync(psum, 0, ((size_t)N_GRAPHS * F_OUT + N_GRAPHS) * 4, stream);

    const int* row = edges;
    const int* col = edges + N_EDGES;

    lin_hist_k<<<NB_LINB + NCHK, 256, 0, stream>>>(node_feat, W, z, col, H);
    scanH1_k<<<MB_H, 1024, 0, stream>>>(H, bsumH);
    scanH2_k<<<1, 256, 0, stream>>>(bsumH);
    scanH3_k<<<MB_H, 1024, 0, stream>>>(H, bsumH);
    scatter_k<<<NCHK, 256, 0, stream>>>(row, col, H, part);
    csr_k<<<NBKT, 256, 0, stream>>>(H, part, bucketF, deg, offs, dis, (unsigned*)z);
    gather_pool_k<<<N_NODES / 32, 256, 0, stream>>>(z, offs, deg, bucketF,
                                                    dis, batch, b, psum, pcnt);
    final_k<<<(N_GRAPHS * F_OUT + 255) / 256, 256, 0, stream>>>(psum, pcnt, (float*)d_out);
}

// Round 13
// 118.767 us; speedup vs baseline: 4.8752x; 1.0037x over previous
//
#include <hip/hip_runtime.h>

#define N_NODES  100000
#define N_EDGES  1250000
#define F_IN     128
#define F_OUT    64
#define N_GRAPHS 256
#define NB_LIN   1563          // total 64-node linear tiles
#define NB_LINB  391           // MFMA blocks; 4 tiles each, W staged once
#define NBKT     782           // coarse buckets: col>>7 (128 nodes each)
#define NCHK     256           // edge chunks
#define CHKSZ    4883          // ceil(E/NCHK); 256*4883 = 1250048
#define M_H      (NBKT * NCHK) // 200192 histogram cells
#define MB_H     196           // ceil(M_H/1024)
#define BKT_CAP  2048          // max edges per bucket (mean 1600, 11 sigma)

typedef __attribute__((ext_vector_type(8))) short short8;   // 8 bf16 (4 VGPRs)
typedef __attribute__((ext_vector_type(4))) float f32x4;

static __device__ __forceinline__ unsigned short f2bf(float f) {
    unsigned u = __builtin_bit_cast(unsigned, f);
    u += 0x7fff + ((u >> 16) & 1);            // RNE
    return (unsigned short)(u >> 16);
}
static __device__ __forceinline__ float bf2f(unsigned short h) {
    unsigned u = ((unsigned)h) << 16;
    return __builtin_bit_cast(float, u);
}
static __device__ __forceinline__ float bflo(unsigned v) {   // low bf16 of packed u32
    return __builtin_bit_cast(float, v << 16);
}
static __device__ __forceinline__ float bfhi(unsigned v) {   // high bf16 of packed u32
    return __builtin_bit_cast(float, v & 0xffff0000u);
}

// ---------------- chunk histograms (LDS counters, no global atomics) ----------------
__global__ __launch_bounds__(256) void hist_k(const int* __restrict__ col,
                                              int* __restrict__ H) {
    __shared__ int cnt[NBKT];
    int c = blockIdx.x, tid = threadIdx.x;
    for (int b = tid; b < NBKT; b += 256) cnt[b] = 0;
    __syncthreads();
    int s = c * CHKSZ;
    int e = s + CHKSZ; if (e > N_EDGES) e = N_EDGES;
    for (int i = s + tid; i < e; i += 256)
        atomicAdd(&cnt[col[i] >> 7], 1);       // LDS atomic: ~1 lane-op/edge
    __syncthreads();
    for (int b = tid; b < NBKT; b += 256)
        H[b * NCHK + c] = cnt[b];
}

// ---------------- exclusive scan of H (lexicographic (bucket, chunk)) ----------
__global__ __launch_bounds__(1024) void scanH1_k(int* __restrict__ H, int* __restrict__ bsum) {
    __shared__ int lds[1024];
    int tid = threadIdx.x;
    int i = blockIdx.x * 1024 + tid;
    int v = (i < M_H) ? H[i] : 0;
    lds[tid] = v;
    __syncthreads();
    for (int off = 1; off < 1024; off <<= 1) {
        int t = (tid >= off) ? lds[tid - off] : 0;
        __syncthreads();
        lds[tid] += t;
        __syncthreads();
    }
    if (i < M_H) H[i] = lds[tid] - v;
    if (tid == 1023) bsum[blockIdx.x] = lds[tid];
}

__global__ __launch_bounds__(256) void scanH2_k(int* __restrict__ bsum) {
    __shared__ int lds[256];
    int tid = threadIdx.x;
    int v = (tid < MB_H) ? bsum[tid] : 0;
    lds[tid] = v;
    __syncthreads();
    for (int off = 1; off < 256; off <<= 1) {
        int t = (tid >= off) ? lds[tid - off] : 0;
        __syncthreads();
        lds[tid] += t;
        __syncthreads();
    }
    if (tid < MB_H) bsum[tid] = lds[tid] - v;
}

__global__ __launch_bounds__(1024) void scanH3_k(int* __restrict__ H, const int* __restrict__ bsum) {
    int i = blockIdx.x * 1024 + threadIdx.x;
    if (i < M_H) H[i] += bsum[blockIdx.x];
}

// ---------------- fused: scatter-partition + MFMA linear (overlap) ----------------
// Blocks [0, NCHK): partition edges into coarse buckets via LDS cursors.
// Blocks [NCHK, NCHK+NB_LINB): z = x@W^T (bf16 MFMA), 4 node-tiles each.
// The latency-bound scatter hides under the MFMA-bound linear in one dispatch.
__global__ __launch_bounds__(256) void scatter_lin_k(const int* __restrict__ row,
                                                     const int* __restrict__ col,
                                                     const int* __restrict__ Hs,
                                                     int2* __restrict__ part,
                                                     const float* __restrict__ x,
                                                     const float* __restrict__ W,
                                                     unsigned short* __restrict__ z) {
    __shared__ unsigned smem[2 * 64 * 64];     // 32 KB, overlaid per path
    int tid = threadIdx.x;

    if (blockIdx.x < NCHK) {
        int* cur = (int*)smem;                 // NBKT cursors overlay
        int c = blockIdx.x;
        for (int b = tid; b < NBKT; b += 256) cur[b] = Hs[b * NCHK + c];
        __syncthreads();
        int s = c * CHKSZ;
        int e = s + CHKSZ; if (e > N_EDGES) e = N_EDGES;
        for (int i = s + tid; i < e; i += 256) {
            int cc = col[i], rr = row[i];
            int p = atomicAdd(&cur[cc >> 7], 1);      // LDS atomic w/ return
            part[p] = make_int2(rr, cc);
        }
        return;
    }

    // ---- linear section ----
    unsigned* xs = smem;
    unsigned* ws = smem + 64 * 64;
    int lb = blockIdx.x - NCHK;

    #pragma unroll
    for (int rr = 0; rr < 8; ++rr) {
        int idx = rr * 256 + tid;
        int n = idx >> 5, q = idx & 31;
        int d   = (n << 6) + (q << 1);
        int sdw = (n & 7) << 2;
        const float4 wv = *(const float4*)(W + (size_t)n * F_IN + q * 4);
        ws[(d ^ sdw)]     = (unsigned)f2bf(wv.x) | ((unsigned)f2bf(wv.y) << 16);
        ws[(d ^ sdw) + 1] = (unsigned)f2bf(wv.z) | ((unsigned)f2bf(wv.w) << 16);
    }

    int lane = tid & 63;
    int wv_  = tid >> 6;
    int m0   = wv_ << 4;
    int lr   = lane & 15;
    int lg   = lane >> 4;

    for (int t4 = 0; t4 < 4; ++t4) {
        int tile = lb * 4 + t4;
        if (tile >= NB_LIN) break;
        int base = tile * 64;
        int nmax = N_NODES - base; if (nmax > 64) nmax = 64;

        #pragma unroll
        for (int rr = 0; rr < 8; ++rr) {
            int idx = rr * 256 + tid;
            int n = idx >> 5, q = idx & 31;
            int d   = (n << 6) + (q << 1);
            int sdw = (n & 7) << 2;
            float4 xv = make_float4(0.f, 0.f, 0.f, 0.f);
            if (n < nmax) xv = *(const float4*)(x + (size_t)(base + n) * F_IN + q * 4);
            xs[(d ^ sdw)]     = (unsigned)f2bf(xv.x) | ((unsigned)f2bf(xv.y) << 16);
            xs[(d ^ sdw) + 1] = (unsigned)f2bf(xv.z) | ((unsigned)f2bf(xv.w) << 16);
        }
        __syncthreads();

        f32x4 acc0 = (f32x4)(0.f), acc1 = (f32x4)(0.f);
        f32x4 acc2 = (f32x4)(0.f), acc3 = (f32x4)(0.f);

        #pragma unroll
        for (int t = 0; t < 4; ++t) {
            int nn = m0 + lr;
            int da = ((nn << 6) + (t << 4) + (lg << 2)) ^ ((nn & 7) << 2);
            short8 a = *(const short8*)(xs + da);
            #pragma unroll
            for (int ff = 0; ff < 4; ++ff) {
                int f  = (ff << 4) + lr;
                int db = ((f << 6) + (t << 4) + (lg << 2)) ^ ((f & 7) << 2);
                short8 b = *(const short8*)(ws + db);
                f32x4 c = (ff == 0) ? acc0 : (ff == 1) ? acc1 : (ff == 2) ? acc2 : acc3;
                c = __builtin_amdgcn_mfma_f32_16x16x32_bf16(a, b, c, 0, 0, 0);
                if (ff == 0) acc0 = c; else if (ff == 1) acc1 = c;
                else if (ff == 2) acc2 = c; else acc3 = c;
            }
        }

        #pragma unroll
        for (int r = 0; r < 4; ++r) {
            int node = m0 + (lg << 2) + r;
            if (node < nmax) {
                size_t o = (size_t)(base + node) * F_OUT + lr;
                z[o +  0] = f2bf(acc0[r]);
                z[o + 16] = f2bf(acc1[r]);
                z[o + 32] = f2bf(acc2[r]);
                z[o + 48] = f2bf(acc3[r]);
            }
        }
        __syncthreads();
    }
}

// ---------------- per-bucket CSR finalize: deg/offs/dis + place rows + scale z --------
__global__ __launch_bounds__(256) void csr_k(const int* __restrict__ Hs,
                                             const int2* __restrict__ part,
                                             int* __restrict__ bucketF,
                                             int* __restrict__ deg,
                                             int* __restrict__ offs,
                                             float* __restrict__ dis,
                                             unsigned* __restrict__ z32) {
    __shared__ int rowL[BKT_CAP];
    __shared__ int colL[BKT_CAP];
    __shared__ int cnt[128], offsL[128], curL[128], scanT[128];
    __shared__ float disL[128];
    int b = blockIdx.x, tid = threadIdx.x;
    int s = Hs[b * NCHK];
    int e = (b < NBKT - 1) ? Hs[(b + 1) * NCHK] : N_EDGES;
    int m = e - s;

    if (tid < 128) cnt[tid] = 0;
    __syncthreads();
    for (int i = tid; i < m; i += 256) {
        int2 pr = part[s + i];
        rowL[i] = pr.x;
        int cl = pr.y & 127;
        colL[i] = cl;
        atomicAdd(&cnt[cl], 1);
    }
    __syncthreads();
    if (tid < 128) scanT[tid] = cnt[tid];
    __syncthreads();
    for (int off = 1; off < 128; off <<= 1) {
        int v = (tid < 128 && tid >= off) ? scanT[tid - off] : 0;
        __syncthreads();
        if (tid < 128) scanT[tid] += v;
        __syncthreads();
    }
    if (tid < 128) {
        int ex = scanT[tid] - cnt[tid];
        offsL[tid] = ex;
        curL[tid]  = ex;
        float d = rsqrtf((float)cnt[tid] + 1.0f);
        disL[tid] = d;
        int node = b * 128 + tid;
        if (node < N_NODES) {
            deg[node]  = cnt[tid];
            offs[node] = s + ex;
            dis[node]  = d;
        }
    }
    __syncthreads();
    for (int i = tid; i < m; i += 256) {
        int cl = colL[i];
        int p = atomicAdd(&curL[cl], 1);
        bucketF[s + p] = rowL[i];
    }
    // scale z in place: y = dis * z (node = tid>>1, 16 u32 each)
    int node = tid >> 1, half = tid & 1;
    int gnode = b * 128 + node;
    if (gnode < N_NODES) {
        float d = disL[node];
        unsigned* zp = z32 + (size_t)gnode * 32 + half * 16;
        #pragma unroll
        for (int k = 0; k < 16; ++k) {
            unsigned v = zp[k];
            zp[k] = (unsigned)f2bf(d * bflo(v)) | ((unsigned)f2bf(d * bfhi(v)) << 16);
        }
    }
}

// ---------------- gather_v6: staged 8+8 loads, packed select, high VGPR budget -------
// Wave handles 8 consecutive nodes. lane = (eo = lane>>5 edge slot, fp = lane&31
// feature pair u32). Stage 8 bucket indices, then 8 payloads (16 loads in flight),
// then unpack+add. Invalid slots zeroed by ONE cndmask on the packed u32.
__global__ __launch_bounds__(256, 4) void gather_pool_k(const unsigned short* __restrict__ y,
                                                        const int* __restrict__ offs,
                                                        const int* __restrict__ deg,
                                                        const int* __restrict__ bucket,
                                                        const float* __restrict__ dis,
                                                        const int* __restrict__ batch,
                                                        const float* __restrict__ bias,
                                                        float* __restrict__ psum,
                                                        int* __restrict__ pcnt) {
    int lane = threadIdx.x & 63;
    int wid  = threadIdx.x >> 6;
    int i0   = (blockIdx.x * 4 + wid) * 8;   // 100000 = 3125 * 32
    int eo   = lane >> 5;                    // edge slot 0/1
    int fp   = lane & 31;                    // feature pair: feats 2fp, 2fp+1
    float bx = bias[2 * fp], by = bias[2 * fp + 1];
    const unsigned short* yb = y + 2 * fp;

    int   om = (lane < 8) ? offs[i0 + lane]  : 0;
    int   dm = (lane < 8) ? deg[i0 + lane]   : 0;
    float sm = (lane < 8) ? dis[i0 + lane]   : 0.f;
    int   gm = (lane < 8) ? batch[i0 + lane] : 0;

    float rx = 0.f, ry = 0.f;
    int cur = -1, runlen = 0;
    #pragma unroll
    for (int n = 0; n < 8; ++n) {
        int i = i0 + n;
        int s = __shfl(om, n);
        int e = s + __shfl(dm, n);

        unsigned sv = *(const unsigned*)(yb + (size_t)i * F_OUT);
        float ax = (eo == 0) ? bflo(sv) : 0.f;
        float ay = (eo == 0) ? bfhi(sv) : 0.f;

        for (int j = s; j < e; j += 16) {
            int rr[8];
            #pragma unroll
            for (int u = 0; u < 8; ++u) {           // 8 independent bucket loads
                int id = j + 2 * u + eo;
                rr[u] = bucket[(id < e) ? id : e - 1];
            }
            unsigned wv[8];
            #pragma unroll
            for (int u = 0; u < 8; ++u) {           // 8 independent y loads
                unsigned w = *(const unsigned*)(yb + (size_t)rr[u] * F_OUT);
                wv[u] = (j + 2 * u + eo < e) ? w : 0u;   // single packed cndmask
            }
            #pragma unroll
            for (int u = 0; u < 8; ++u) {
                ax += bflo(wv[u]);
                ay += bfhi(wv[u]);
            }
        }
        ax += __shfl_xor(ax, 32);
        ay += __shfl_xor(ay, 32);

        float di = __shfl(sm, n);
        float vx = fmaxf(fmaf(di, ax, bx), 0.f);
        float vy = fmaxf(fmaf(di, ay, by), 0.f);
        int g = __shfl(gm, n);
        if (g != cur) {
            if (cur >= 0 && eo == 0) {
                atomicAdd(&psum[cur * F_OUT + 2 * fp],     rx);
                atomicAdd(&psum[cur * F_OUT + 2 * fp + 1], ry);
                if (lane == 0) atomicAdd(&pcnt[cur], runlen);
            }
            cur = g; rx = 0.f; ry = 0.f; runlen = 0;
        }
        rx += vx; ry += vy; runlen++;
    }
    if (cur >= 0 && eo == 0) {
        atomicAdd(&psum[cur * F_OUT + 2 * fp],     rx);
        atomicAdd(&psum[cur * F_OUT + 2 * fp + 1], ry);
        if (lane == 0) atomicAdd(&pcnt[cur], runlen);
    }
}

// ---------------- out = psum / max(count,1) ----------------
__global__ __launch_bounds__(256) void final_k(const float* __restrict__ psum,
                                               const int* __restrict__ pcnt,
                                               float* __restrict__ out) {
    int t = blockIdx.x * blockDim.x + threadIdx.x;
    if (t < N_GRAPHS * F_OUT) {
        int g = t >> 6;
        float c = (float)(pcnt[g] > 1 ? pcnt[g] : 1);
        out[t] = psum[t] / c;
    }
}

extern "C" void kernel_launch(void* const* d_in, const int* in_sizes, int n_in,
                              void* d_out, int out_size, void* d_ws, size_t ws_size,
                              hipStream_t stream) {
    const float* node_feat = (const float*)d_in[0];
    const int*   edges     = (const int*)d_in[1];   // [2, E] flat: row then col
    const int*   batch     = (const int*)d_in[2];
    const float* W         = (const float*)d_in[3];
    const float* b         = (const float*)d_in[4];

    // workspace carve-up (~30 MB)
    unsigned short* z = (unsigned short*)d_ws;               // N*64 bf16 (scaled in place)
    int2*  part    = (int2*)(z + (size_t)N_NODES * F_OUT);   // E pairs
    int*   bucketF = (int*)(part + N_EDGES);                 // E
    int*   H       = bucketF + N_EDGES;                      // M_H
    int*   bsumH   = H + M_H;                                // 256
    int*   deg     = bsumH + 256;                            // N
    int*   offs    = deg + N_NODES;                          // N
    float* dis     = (float*)(offs + N_NODES);               // N
    float* psum    = dis + N_NODES;                          // G*64
    int*   pcnt    = (int*)(psum + N_GRAPHS * F_OUT);        // G

    hipMemsetAsync(psum, 0, ((size_t)N_GRAPHS * F_OUT + N_GRAPHS) * 4, stream);

    const int* row = edges;
    const int* col = edges + N_EDGES;

    hist_k<<<NCHK, 256, 0, stream>>>(col, H);
    scanH1_k<<<MB_H, 1024, 0, stream>>>(H, bsumH);
    scanH2_k<<<1, 256, 0, stream>>>(bsumH);
    scanH3_k<<<MB_H, 1024, 0, stream>>>(H, bsumH);
    scatter_lin_k<<<NCHK + NB_LINB, 256, 0, stream>>>(row, col, H, part,
                                                      node_feat, W, z);
    csr_k<<<NBKT, 256, 0, stream>>>(H, part, bucketF, deg, offs, dis, (unsigned*)z);
    gather_pool_k<<<N_NODES / 32, 256, 0, stream>>>(z, offs, deg, bucketF,
                                                    dis, batch, b, psum, pcnt);
    final_k<<<(N_GRAPHS * F_OUT + 255) / 256, 256, 0, stream>>>(psum, pcnt, (float*)d_out);
}